// Round 11
// baseline (978.192 us; speedup 1.0000x reference)
//
#include <hip/hip_runtime.h>

#define NT 4096
#define DD 1152
#define D3 3456
#define D3P 3584
#define MLP_R 4304
#define MLP_P 4352
#define KP 640

typedef unsigned short u16;
typedef short v8s __attribute__((ext_vector_type(8)));
typedef float v4f __attribute__((ext_vector_type(4)));

__device__ __forceinline__ u16 f2b(float f) {
    unsigned int u = __builtin_bit_cast(unsigned int, f);
    u += 0x7fffu + ((u >> 16) & 1u);          // round-to-nearest-even
    return (u16)(u >> 16);
}
__device__ __forceinline__ float b2f(u16 s) {
    unsigned int u = ((unsigned int)s) << 16;
    return __builtin_bit_cast(float, u);
}

__device__ __forceinline__ void async16(const void* g, void* l) {
    __builtin_amdgcn_global_load_lds(
        (const __attribute__((address_space(1))) void*)g,
        (__attribute__((address_space(3))) void*)l, 16, 0, 0);
}

// raw LDS byte offset of a generic pointer known to live in LDS
__device__ __forceinline__ unsigned lds_off(const void* p) {
    return (unsigned)(size_t)(const __attribute__((address_space(3))) void*)p;
}
// asm ds_read_b128: invisible to the memory legalizer, so the compiler does
// NOT insert s_waitcnt vmcnt(0) guards against outstanding global_load_lds.
__device__ __forceinline__ v8s ldsr(unsigned byte_off) {
    v8s r;
    asm volatile("ds_read_b128 %0, %1" : "=v"(r) : "v"(byte_off));
    return r;
}

__device__ __forceinline__ float gelu_f(float t) {
    float u = t * (0.7978845608028654f + 0.03567740814183026f * t * t);
    return t / (1.0f + __expf(-2.0f * u));
}

// ---------------------------------------------------------------------------
// 128x128 2-phase GEMM, 2 blocks/CU. ONLY user: FC1 (1088 blocks).
// R10: m-fast XCD decode kept (FC1 left the top-5 with it).
// EPI: 2 = bf16(gelu(acc+bias))
// ---------------------------------------------------------------------------
template<int EPI>
__global__ __launch_bounds__(512, 4)
void gemm2p(const u16* __restrict__ A, const u16* __restrict__ B, int ld,
            int Kdim, const float* __restrict__ bias,
            const float* __restrict__ aux, float* __restrict__ outf,
            u16* __restrict__ outb, int ldc, int NNT)
{
    __shared__ __align__(128) union { u16 kl[2][16384]; float sc[8][64][17]; } sm;
    const int tid  = threadIdx.x, lane = tid & 63, wave = tid >> 6;
    const int wr   = wave >> 2, wc = wave & 3;
    const int fr   = lane & 15, kqh = lane >> 4;

    // XCD-compact, m-fast within chunk (bijective when chunk % NNT == 0)
    const int nwg   = gridDim.x;
    const int bidx  = (int)blockIdx.x;
    const int chunk = nwg >> 3;
    const int xcd   = bidx & 7;
    const int j     = bidx >> 3;
    const int MXCD  = chunk / NNT;
    const int mt    = xcd * MXCD + (j % MXCD);
    const int nt    = j / MXCD;
    const int bm0   = mt * 128, bn0 = nt * 128;

    const int c    = tid;
    const int s_lr = (c >> 7) * 16 + ((c >> 2) & 15);
    const int s_lc = ((((c >> 6) & 1) * 4) + ((c & 3) ^ (((c >> 5) & 1) << 1))) * 8;
    const size_t s_off = (size_t)s_lr * ld + s_lc;
    const unsigned koff2 = (unsigned)(fr * 64 + ((kqh * 16) ^ ((fr & 8) << 2)));

    u16* kb = sm.kl[0];
    const unsigned lbase = lds_off(kb);

    auto stage = [&](int bi, int reg, const u16* gRowBase) {
        u16* lb = kb + bi * 16384 + reg * 4096;
        async16(gRowBase + s_off, lb + tid * 8);
        async16(gRowBase + s_off + (size_t)64 * ld, lb + (512 + tid) * 8);
    };
    auto srcA = [&](int t) { return A + (size_t)bm0 * ld + t * 64; };
    auto srcB = [&](int t) { return B + (size_t)bn0 * ld + t * 64; };

    v4f acc[4][2];
    const v4f vzero = {0.f, 0.f, 0.f, 0.f};
#pragma unroll
    for (int i = 0; i < 4; ++i) { acc[i][0] = vzero; acc[i][1] = vzero; }

    const int NKT = Kdim >> 6;

    stage(0, 0, srcA(0));
    stage(0, 2, srcB(0));
    if (NKT > 1) {
        stage(1, 2, srcB(1));
        asm volatile("s_waitcnt vmcnt(2)" ::: "memory");
    } else {
        asm volatile("s_waitcnt vmcnt(0)" ::: "memory");
    }
    __builtin_amdgcn_s_barrier();

    v8s a[8], b0f[2], b1f[2];
    for (int t = 0; t < NKT; ++t) {
        const int bi = t & 1;
        const unsigned AB = lbase + bi * 32768;
        const unsigned BB = AB + 16384;

#pragma unroll
        for (int mi = 0; mi < 4; ++mi)
#pragma unroll
            for (int ks = 0; ks < 2; ++ks)
                a[mi * 2 + ks] = ldsr(AB + ((wr * 4 + mi) * 2 + ks) * 1024 + koff2);
#pragma unroll
        for (int ks = 0; ks < 2; ++ks)
            b0f[ks] = ldsr(BB + ((wc * 2 + 0) * 2 + ks) * 1024 + koff2);
#pragma unroll
        for (int ks = 0; ks < 2; ++ks)
            b1f[ks] = ldsr(BB + ((wc * 2 + 1) * 2 + ks) * 1024 + koff2);
        if (t + 1 < NKT) stage(bi ^ 1, 0, srcA(t + 1));
        __builtin_amdgcn_s_barrier();
        asm volatile("s_waitcnt lgkmcnt(0)" ::: "memory");
        __builtin_amdgcn_sched_barrier(0);
        __builtin_amdgcn_s_setprio(1);
#pragma unroll
        for (int mi = 0; mi < 4; ++mi)
#pragma unroll
            for (int ks = 0; ks < 2; ++ks)
                acc[mi][0] = __builtin_amdgcn_mfma_f32_16x16x32_bf16(
                    a[mi * 2 + ks], b0f[ks], acc[mi][0], 0, 0, 0);
        __builtin_amdgcn_s_setprio(0);
        __builtin_amdgcn_s_barrier();

        if (t + 2 < NKT) stage(bi, 2, srcB(t + 2));
        __builtin_amdgcn_s_setprio(1);
#pragma unroll
        for (int mi = 0; mi < 4; ++mi)
#pragma unroll
            for (int ks = 0; ks < 2; ++ks)
                acc[mi][1] = __builtin_amdgcn_mfma_f32_16x16x32_bf16(
                    a[mi * 2 + ks], b1f[ks], acc[mi][1], 0, 0, 0);
        __builtin_amdgcn_s_setprio(0);
        if (t + 2 < NKT) { asm volatile("s_waitcnt vmcnt(2)" ::: "memory"); }
        else             { asm volatile("s_waitcnt vmcnt(0)" ::: "memory"); }
        __builtin_amdgcn_s_barrier();
    }

    const int cn = lane & 15;
    const int cm = (lane >> 4) * 4;
    float (*S)[17] = sm.sc[wave];
    const int gm = bm0 + wr * 64 + lane;
#pragma unroll
    for (int jp = 0; jp < 2; ++jp) {
        __syncthreads();
#pragma unroll
        for (int i = 0; i < 4; ++i)
#pragma unroll
            for (int r = 0; r < 4; ++r)
                S[i * 16 + cm + r][cn] = acc[i][jp][r];
        __syncthreads();
        const int gn0 = bn0 + wc * 32 + jp * 16;
        float v[16];
#pragma unroll
        for (int cc = 0; cc < 16; ++cc) v[cc] = S[lane][cc];
        union { u16 us[16]; uint4 q4[2]; } o;
#pragma unroll
        for (int cc = 0; cc < 16; ++cc) {
            float tv = v[cc];
            if constexpr (EPI >= 1) tv += bias[gn0 + cc];
            if constexpr (EPI == 2) tv = gelu_f(tv);
            o.us[cc] = f2b(tv);
        }
        uint4* dst = (uint4*)(outb + (size_t)gm * ldc + gn0);
        dst[0] = o.q4[0];
        dst[1] = o.q4[1];
    }
}

// ---------------------------------------------------------------------------
// 256x256 8-phase GEMM — round-4 schedule (proven). 1 block/CU; best for
// grids <= 256 blocks (single round). Used by QKV (224) and QKT (256).
// EPI: 0 = bf16 out; 1 = bf16(acc+bias) + fused V-transpose; 2 = gelu
// ---------------------------------------------------------------------------
template<int EPI>
__global__ __launch_bounds__(512, 2)
void gemm8p(const u16* __restrict__ A, const u16* __restrict__ B, int ld,
            int Kdim, const float* __restrict__ bias,
            u16* __restrict__ outb, int ldc, int NNT, u16* __restrict__ vt)
{
    __shared__ __align__(128) union { u16 kl[2][32768]; u16 ep[8][8192]; } sm;
    const int tid  = threadIdx.x, lane = tid & 63, wave = tid >> 6;
    const int wr   = wave >> 2, wc = wave & 3;
    const int fr   = lane & 15, kqh = lane >> 4;

    const int nwg  = gridDim.x;
    const int bidx = (int)blockIdx.x;
    const int wg   = (bidx & 7) * (nwg >> 3) + (bidx >> 3);
    const int mt   = wg / NNT, nt = wg % NNT;
    const int bm0  = mt * 256, bn0 = nt * 256;

    const int c    = tid;
    const int s_lr = (c >> 7) * 16 + ((c >> 2) & 15);
    const int s_lc = ((((c >> 6) & 1) * 4) + ((c & 3) ^ (((c >> 5) & 1) << 1))) * 8;
    const size_t s_off = (size_t)s_lr * ld + s_lc;
    const unsigned koff2 = (unsigned)(fr * 64 + ((kqh * 16) ^ ((fr & 8) << 2)));

    u16* kb = sm.kl[0];
    const unsigned lbase = lds_off(kb);

    auto stage = [&](int bi, int reg, const u16* gRowBase) {
        u16* lb = kb + bi * 32768 + reg * 4096;
        async16(gRowBase + s_off, lb + tid * 8);
        async16(gRowBase + s_off + (size_t)64 * ld, lb + (512 + tid) * 8);
    };
    auto srcA = [&](int h, int t) { return A + (size_t)(bm0 + h * 128) * ld + t * 64; };
    auto srcB = [&](int h, int t) { return B + (size_t)(bn0 + h * 128) * ld + t * 64; };

    v4f acc[8][4];
    const v4f vzero = {0.f, 0.f, 0.f, 0.f};
#pragma unroll
    for (int i = 0; i < 8; ++i)
#pragma unroll
        for (int j = 0; j < 4; ++j) acc[i][j] = vzero;

    const int NKT = Kdim >> 6;

    stage(0, 4, srcB(0, 0));
    stage(0, 6, srcB(1, 0));
    stage(0, 0, srcA(0, 0));
    stage(0, 2, srcA(1, 0));
    if (NKT > 1) {
        stage(1, 4, srcB(0, 1));
        stage(1, 6, srcB(1, 1));
        asm volatile("s_waitcnt vmcnt(4)" ::: "memory");
    } else {
        asm volatile("s_waitcnt vmcnt(0)" ::: "memory");
    }
    __builtin_amdgcn_s_barrier();

    v8s a[8], b0f[4], b1f[4];
    for (int t = 0; t < NKT; ++t) {
        const int bi = t & 1;
        const unsigned AB = lbase + bi * 65536 + wr * 16384;
        const unsigned BB = lbase + bi * 65536 + 32768 + (wc >> 1) * 16384;
        const unsigned bs = (wc & 1) * 8192;

        // phase 1
#pragma unroll
        for (int mi = 0; mi < 4; ++mi)
#pragma unroll
            for (int ks = 0; ks < 2; ++ks)
                a[mi * 2 + ks] = ldsr(AB + (mi * 2 + ks) * 1024 + koff2);
#pragma unroll
        for (int nj = 0; nj < 2; ++nj)
#pragma unroll
            for (int ks = 0; ks < 2; ++ks)
                b0f[nj * 2 + ks] = ldsr(BB + bs + (nj * 2 + ks) * 1024 + koff2);
        if (t + 1 < NKT) stage(bi ^ 1, 0, srcA(0, t + 1));
        __builtin_amdgcn_s_barrier();
        asm volatile("s_waitcnt lgkmcnt(0)" ::: "memory");
        __builtin_amdgcn_sched_barrier(0);
        __builtin_amdgcn_s_setprio(1);
#pragma unroll
        for (int mi = 0; mi < 4; ++mi)
#pragma unroll
            for (int nj = 0; nj < 2; ++nj)
#pragma unroll
                for (int ks = 0; ks < 2; ++ks)
                    acc[mi][nj] = __builtin_amdgcn_mfma_f32_16x16x32_bf16(
                        a[mi * 2 + ks], b0f[nj * 2 + ks], acc[mi][nj], 0, 0, 0);
        __builtin_amdgcn_s_setprio(0);
        __builtin_amdgcn_s_barrier();

        // phase 2
#pragma unroll
        for (int nj = 0; nj < 2; ++nj)
#pragma unroll
            for (int ks = 0; ks < 2; ++ks)
                b1f[nj * 2 + ks] = ldsr(BB + bs + (4 + nj * 2 + ks) * 1024 + koff2);
        if (t + 1 < NKT) stage(bi ^ 1, 2, srcA(1, t + 1));
        __builtin_amdgcn_s_barrier();
        asm volatile("s_waitcnt lgkmcnt(0)" ::: "memory");
        __builtin_amdgcn_sched_barrier(0);
        __builtin_amdgcn_s_setprio(1);
#pragma unroll
        for (int mi = 0; mi < 4; ++mi)
#pragma unroll
            for (int nj = 0; nj < 2; ++nj)
#pragma unroll
                for (int ks = 0; ks < 2; ++ks)
                    acc[mi][2 + nj] = __builtin_amdgcn_mfma_f32_16x16x32_bf16(
                        a[mi * 2 + ks], b1f[nj * 2 + ks], acc[mi][2 + nj], 0, 0, 0);
        __builtin_amdgcn_s_setprio(0);
        __builtin_amdgcn_s_barrier();

        // phase 3
#pragma unroll
        for (int mi = 0; mi < 4; ++mi)
#pragma unroll
            for (int ks = 0; ks < 2; ++ks)
                a[mi * 2 + ks] = ldsr(AB + (8 + mi * 2 + ks) * 1024 + koff2);
        if (t + 2 < NKT) stage(bi, 4, srcB(0, t + 2));
        __builtin_amdgcn_s_barrier();
        asm volatile("s_waitcnt lgkmcnt(0)" ::: "memory");
        __builtin_amdgcn_sched_barrier(0);
        __builtin_amdgcn_s_setprio(1);
#pragma unroll
        for (int mi = 0; mi < 4; ++mi)
#pragma unroll
            for (int nj = 0; nj < 2; ++nj)
#pragma unroll
                for (int ks = 0; ks < 2; ++ks)
                    acc[4 + mi][2 + nj] = __builtin_amdgcn_mfma_f32_16x16x32_bf16(
                        a[mi * 2 + ks], b1f[nj * 2 + ks], acc[4 + mi][2 + nj], 0, 0, 0);
        __builtin_amdgcn_s_setprio(0);
        __builtin_amdgcn_s_barrier();

        // phase 4
        if (t + 2 < NKT) stage(bi, 6, srcB(1, t + 2));
        __builtin_amdgcn_s_barrier();
        __builtin_amdgcn_s_setprio(1);
#pragma unroll
        for (int mi = 0; mi < 4; ++mi)
#pragma unroll
            for (int nj = 0; nj < 2; ++nj)
#pragma unroll
                for (int ks = 0; ks < 2; ++ks)
                    acc[4 + mi][nj] = __builtin_amdgcn_mfma_f32_16x16x32_bf16(
                        a[mi * 2 + ks], b0f[nj * 2 + ks], acc[4 + mi][nj], 0, 0, 0);
        __builtin_amdgcn_s_setprio(0);
        if (t + 2 < NKT) { asm volatile("s_waitcnt vmcnt(4)" ::: "memory"); }
        else             { asm volatile("s_waitcnt vmcnt(0)" ::: "memory"); }
        __builtin_amdgcn_s_barrier();
    }

    asm volatile("s_waitcnt vmcnt(0)" ::: "memory");
    __builtin_amdgcn_s_barrier();
    u16* ew = sm.ep[wave];
    float bcol[4];
    if constexpr (EPI >= 1) {
#pragma unroll
        for (int nj = 0; nj < 4; ++nj)
            bcol[nj] = bias[bn0 + wc * 64 + nj * 16 + fr];
    }
#pragma unroll
    for (int mi = 0; mi < 8; ++mi)
#pragma unroll
        for (int nj = 0; nj < 4; ++nj)
#pragma unroll
            for (int r = 0; r < 4; ++r) {
                int row = mi * 16 + kqh * 4 + r;
                int ec  = nj * 16 + fr;
                float t = acc[mi][nj][r];
                if constexpr (EPI >= 1) t += bcol[nj];
                if constexpr (EPI == 2) t = gelu_f(t);
                ew[row * 64 + (ec ^ (((row >> 2) & 3) << 4))] = f2b(t);
            }
    __syncthreads();
    const int gc = bn0 + wc * 64 + (lane & 7) * 8;
    const bool inV = (EPI == 1) && (vt != nullptr) && gc >= 2304 && gc < D3;
#pragma unroll
    for (int p = 0; p < 16; ++p) {
        int row = p * 8 + (lane >> 3);
        int key = (row >> 2) & 3;
        v8s ch = *(const v8s*)(ew + row * 64 + (((lane & 7) * 8) ^ (key << 4)));
        size_t gm = (size_t)(bm0 + wr * 128 + row);
        *(uint4*)(outb + gm * ldc + gc) = __builtin_bit_cast(uint4, ch);
        if constexpr (EPI == 1) {
            if (inV) {
                union { v8s v; u16 us[8]; } cu; cu.v = ch;
#pragma unroll
                for (int j = 0; j < 8; ++j)
                    vt[(size_t)(gc + j - 2304) * NT + gm] = cu.us[j];
            }
        }
    }
}

// ---------------------------------------------------------------------------
// GEMM: C[m][n] = sum_k A[m][k] * B[n][k]   (B transposed, K contiguous)
// DBUF=1 (MT=64): double-buffered LDS, one barrier per K-step.
// R11: NTB template param — NTB=64 shrinks the N-tile to 64 (LDS 32KB,
// grid x2 = 1152 blocks = 4.5 blocks/CU, ~18 waves/CU) to push past the
// 2.25-blocks/CU occupancy that capped the N=1152 family at ~580 TF.
// EPI: 0 = bf16 out; 2 = bf16(gelu(acc+bias)); 3 = f32 out = aux + acc + bias;
//      4 = f32 out = acc + bias[n] + pos[n][m]  (aux = pos, [D][NT] layout)
// ---------------------------------------------------------------------------
template<int EPI, int MT, int DBUF = 0, int NTB = 128>
__global__ __launch_bounds__(256)
void gemm_bt(const u16* __restrict__ A, int lda,
             const u16* __restrict__ B, int ldb, int Kdim,
             const float* __restrict__ bias, const float* __restrict__ aux,
             float* __restrict__ outf, u16* __restrict__ outb, int ldc,
             u16* __restrict__ vt, int NX)
{
    constexpr int JT = (MT == 128) ? 4 : (NTB >> 6);   // 16-col j-tiles/wave
    constexpr int AR = MT * 8 / 256;                   // A staging rounds
    constexpr int BR = NTB * 8 / 256;                  // B staging rounds
    constexpr int NB = DBUF ? 2 : 1;

    __shared__ union SM {
        struct { u16 a[NB * MT * 64]; u16 b[NB * NTB * 64]; } st;
        float sc[4][64][17];
    } sm;

    const int b    = blockIdx.x;
    const int MY   = (gridDim.x >> 3) / NX;
    const int q    = b >> 3;
    const int m0   = ((b & 7) * MY + q % MY) * MT;
    const int n0   = (q / MY) * NTB;

    const int tid  = threadIdx.x;
    const int lane = tid & 63;
    const int wave = tid >> 6;
    const int wm   = (MT == 128) ? (wave & 1) * 64 : 0;
    const int wn   = (MT == 128) ? (wave >> 1) * 64 : wave * (NTB / 4);
    const int fr   = lane & 15;
    const int kqh  = lane >> 4;
    const int swz  = fr & 7;

    v4f acc[4][JT];
    const v4f vzero = {0.f, 0.f, 0.f, 0.f};
#pragma unroll
    for (int i = 0; i < 4; ++i)
#pragma unroll
        for (int j = 0; j < JT; ++j) acc[i][j] = vzero;

    auto stage = [&](u16* As, u16* Bs, int kt) {
#pragma unroll
        for (int r = 0; r < AR; ++r) {
            int c = r * 256 + tid;
            int row = c >> 3;
            int kc = (c & 7) ^ (row & 7);
            async16(A + (size_t)(m0 + row) * lda + kt + kc * 8, As + c * 8);
        }
#pragma unroll
        for (int r = 0; r < BR; ++r) {
            int c = r * 256 + tid;
            int row = c >> 3;
            int kc = (c & 7) ^ (row & 7);
            async16(B + (size_t)(n0 + row) * ldb + kt + kc * 8, Bs + c * 8);
        }
    };

    auto compute = [&](const u16* As, const u16* Bs) {
#pragma unroll
        for (int ks = 0; ks < 2; ++ks) {
            const int kq = ks * 4 + kqh;
            const int kp = (kq ^ swz) * 8;
            v8s af[4], bf[JT];
#pragma unroll
            for (int i = 0; i < 4; ++i)
                af[i] = *(const v8s*)(As + (wm + i * 16 + fr) * 64 + kp);
#pragma unroll
            for (int j = 0; j < JT; ++j)
                bf[j] = *(const v8s*)(Bs + (wn + j * 16 + fr) * 64 + kp);
#pragma unroll
            for (int i = 0; i < 4; ++i)
#pragma unroll
                for (int j = 0; j < JT; ++j)
                    acc[i][j] = __builtin_amdgcn_mfma_f32_16x16x32_bf16(
                        af[i], bf[j], acc[i][j], 0, 0, 0);
        }
    };

    if constexpr (DBUF) {
        stage(sm.st.a, sm.st.b, 0);
        int cur = 0;
        for (int kt = 0; kt < Kdim; kt += 64) {
            __syncthreads();
            const int nxt = cur ^ 1;
            if (kt + 64 < Kdim)
                stage(sm.st.a + nxt * (MT * 64), sm.st.b + nxt * (NTB * 64), kt + 64);
            compute(sm.st.a + cur * (MT * 64), sm.st.b + cur * (NTB * 64));
            cur = nxt;
        }
    } else {
        for (int kt = 0; kt < Kdim; kt += 64) {
            stage(sm.st.a, sm.st.b, kt);
            __syncthreads();
            compute(sm.st.a, sm.st.b);
            __syncthreads();
        }
    }

    const int cn = lane & 15;
    const int cm = (lane >> 4) * 4;
    float (*S)[17] = sm.sc[wave];
    const int gm = m0 + wm + lane;
#pragma unroll
    for (int jp = 0; jp < JT; ++jp) {
        __syncthreads();
#pragma unroll
        for (int i = 0; i < 4; ++i)
#pragma unroll
            for (int r = 0; r < 4; ++r)
                S[i * 16 + cm + r][cn] = acc[i][jp][r];
        __syncthreads();
        const int gn0 = n0 + wn + jp * 16;
        float v[16];
#pragma unroll
        for (int c = 0; c < 16; ++c) v[c] = S[lane][c];
        if constexpr (EPI <= 2) {
            union { u16 us[16]; uint4 q4[2]; } o;
#pragma unroll
            for (int c = 0; c < 16; ++c) {
                float t = v[c];
                if constexpr (EPI >= 1) t += bias[gn0 + c];
                if constexpr (EPI == 2) t = gelu_f(t);
                o.us[c] = f2b(t);
            }
            uint4* dst = (uint4*)(outb + (size_t)gm * ldc + gn0);
            dst[0] = o.q4[0];
            dst[1] = o.q4[1];
            if constexpr (EPI == 1) {
                if (vt != nullptr && gn0 >= 2304) {
#pragma unroll
                    for (int c = 0; c < 16; ++c)
                        vt[(size_t)(gn0 + c - 2304) * NT + gm] = o.us[c];
                }
            }
        } else if constexpr (EPI == 3) {
            float* dst = outf + (size_t)gm * ldc + gn0;
            const float* ax = aux + (size_t)gm * ldc + gn0;
#pragma unroll
            for (int c = 0; c < 4; ++c) {
                float4 a4 = ((const float4*)ax)[c];
                float4 r4;
                r4.x = a4.x + v[4 * c + 0] + bias[gn0 + 4 * c + 0];
                r4.y = a4.y + v[4 * c + 1] + bias[gn0 + 4 * c + 1];
                r4.z = a4.z + v[4 * c + 2] + bias[gn0 + 4 * c + 2];
                r4.w = a4.w + v[4 * c + 3] + bias[gn0 + 4 * c + 3];
                ((float4*)dst)[c] = r4;
            }
        } else {
            float* dst = outf + (size_t)gm * ldc + gn0;
#pragma unroll
            for (int c = 0; c < 4; ++c) {
                float4 r4;
                r4.x = v[4 * c + 0] + bias[gn0 + 4 * c + 0] + aux[(size_t)(gn0 + 4 * c + 0) * NT + gm];
                r4.y = v[4 * c + 1] + bias[gn0 + 4 * c + 1] + aux[(size_t)(gn0 + 4 * c + 1) * NT + gm];
                r4.z = v[4 * c + 2] + bias[gn0 + 4 * c + 2] + aux[(size_t)(gn0 + 4 * c + 2) * NT + gm];
                r4.w = v[4 * c + 3] + bias[gn0 + 4 * c + 3] + aux[(size_t)(gn0 + 4 * c + 3) * NT + gm];
                ((float4*)dst)[c] = r4;
            }
        }
    }
}

// ---------------------------------------------------------------------------
// LayerNorm over D=1152. 384 threads, 3 elems each. OUTF=1 -> f32, else bf16.
// ---------------------------------------------------------------------------
template<int OUTF>
__global__ __launch_bounds__(384)
void ln_kernel(const float* __restrict__ x, const float* __restrict__ w,
               const float* __restrict__ b, void* __restrict__ out)
{
    const int n = blockIdx.x;
    const int t = threadIdx.x;
    const float* row = x + (size_t)n * DD;
    float v0 = row[t], v1 = row[t + 384], v2 = row[t + 768];
    float s  = v0 + v1 + v2;
    float ss = v0 * v0 + v1 * v1 + v2 * v2;
#pragma unroll
    for (int o = 32; o > 0; o >>= 1) {
        s  += __shfl_down(s, o);
        ss += __shfl_down(ss, o);
    }
    __shared__ float ps[6], pss[6], mh[2];
    if ((t & 63) == 0) { ps[t >> 6] = s; pss[t >> 6] = ss; }
    __syncthreads();
    if (t == 0) {
        float S = 0.f, SS = 0.f;
        for (int i = 0; i < 6; ++i) { S += ps[i]; SS += pss[i]; }
        float m = S / (float)DD;
        float var = SS / (float)DD - m * m;
        mh[0] = m;
        mh[1] = rsqrtf(var + 1e-6f);
    }
    __syncthreads();
    const float m = mh[0], rs = mh[1];
#pragma unroll
    for (int j = 0; j < 3; ++j) {
        int c = t + j * 384;
        float y = (row[c] - m) * rs * w[c] + b[c];
        if constexpr (OUTF) ((float*)out)[(size_t)n * DD + c] = y;
        else                ((u16*)out)[(size_t)n * DD + c]   = f2b(y);
    }
}

// ---------------------------------------------------------------------------
// Softmax over rows of bf16 scores [NT x NT], in place, with scale.
// ---------------------------------------------------------------------------
__global__ __launch_bounds__(256)
void softmax_kernel(u16* __restrict__ s)
{
    const float SC = 0.029462782549439484f;  // 1/sqrt(1152)
    const int row = blockIdx.x;
    const int t = threadIdx.x;
    u16* p = s + (size_t)row * NT + t * 16;
    uint4 u0 = *(const uint4*)p;
    uint4 u1 = *(const uint4*)(p + 8);
    float v[16];
    unsigned int w[8] = {u0.x, u0.y, u0.z, u0.w, u1.x, u1.y, u1.z, u1.w};
#pragma unroll
    for (int i = 0; i < 8; ++i) {
        v[2 * i]     = b2f((u16)(w[i] & 0xffffu)) * SC;
        v[2 * i + 1] = b2f((u16)(w[i] >> 16)) * SC;
    }
    float mx = -1e30f;
#pragma unroll
    for (int i = 0; i < 16; ++i) mx = fmaxf(mx, v[i]);
#pragma unroll
    for (int o = 32; o > 0; o >>= 1) mx = fmaxf(mx, __shfl_down(mx, o));
    __shared__ float red[4];
    __shared__ float bc;
    if ((t & 63) == 0) red[t >> 6] = mx;
    __syncthreads();
    if (t == 0) bc = fmaxf(fmaxf(red[0], red[1]), fmaxf(red[2], red[3]));
    __syncthreads();
    const float M = bc;
    float sum = 0.f;
#pragma unroll
    for (int i = 0; i < 16; ++i) { v[i] = __expf(v[i] - M); sum += v[i]; }
#pragma unroll
    for (int o = 32; o > 0; o >>= 1) sum += __shfl_down(sum, o);
    __syncthreads();
    if ((t & 63) == 0) red[t >> 6] = sum;
    __syncthreads();
    if (t == 0) bc = red[0] + red[1] + red[2] + red[3];
    __syncthreads();
    const float inv = 1.0f / bc;
    union { u16 us[8]; uint4 u4; } o0, o1;
#pragma unroll
    for (int i = 0; i < 8; ++i) o0.us[i] = f2b(v[i] * inv);
#pragma unroll
    for (int i = 0; i < 8; ++i) o1.us[i] = f2b(v[8 + i] * inv);
    *(uint4*)p = o0.u4;
    *(uint4*)(p + 8) = o1.u4;
}

// ---------------------------------------------------------------------------
// im2col: img [3][896][896] -> a [NT][KP] bf16 (k = cin*196+py*14+px, pad->0)
// ---------------------------------------------------------------------------
__global__ __launch_bounds__(256)
void im2col_kernel(const float* __restrict__ img, u16* __restrict__ a)
{
    const int k = blockIdx.x * 256 + threadIdx.x;
    const int n = blockIdx.y;
    if (k >= KP) return;
    float v = 0.f;
    if (k < 588) {
        int cin = k / 196;
        int rr = k - cin * 196;
        int py = rr / 14;
        int px = rr - py * 14;
        int gy = (n >> 6) * 14 + py;
        int gx = (n & 63) * 14 + px;
        v = img[(size_t)cin * 896 * 896 + (size_t)gy * 896 + gx];
    }
    a[(size_t)n * KP + k] = f2b(v);
}

// ---------------------------------------------------------------------------
// One fused, float4-vectorized weight conversion/pad kernel.
// QKV weights/bias PADDED to D3P=3584 rows (zeros beyond 3456).
// ---------------------------------------------------------------------------
constexpr int CV_S0 = 2 * D3P * DD / 4;
constexpr int CV_S1 = CV_S0 + 2 * DD * DD / 4;
constexpr int CV_S2 = CV_S1 + 2 * MLP_P * DD / 4;
constexpr int CV_S3 = CV_S2 + 2 * DD * MLP_P / 4;
constexpr int CV_S4 = CV_S3 + DD * KP / 4;
constexpr int CV_S5 = CV_S4 + 2 * MLP_P / 4;
constexpr int CV_S6 = CV_S5 + 2 * D3P / 4;
constexpr int CV_BLOCKS = (CV_S6 + 255) / 256;

__device__ __forceinline__ void store_bf4(u16* p, float4 f) {
    union { u16 s[4]; uint2 d; } o;
    o.s[0] = f2b(f.x); o.s[1] = f2b(f.y); o.s[2] = f2b(f.z); o.s[3] = f2b(f.w);
    *(uint2*)p = o.d;
}

__global__ __launch_bounds__(256)
void convert_all(const float* __restrict__ qkv_w, const float* __restrict__ proj_w,
                 const float* __restrict__ fc1_w, const float* __restrict__ fc2_w,
                 const float* __restrict__ patch_w, const float* __restrict__ fc1_b,
                 const float* __restrict__ qkv_b,
                 u16* __restrict__ w_qkv, u16* __restrict__ w_proj,
                 u16* __restrict__ w_fc1, u16* __restrict__ w_fc2,
                 u16* __restrict__ w_pat, float* __restrict__ fc1b_p,
                 float* __restrict__ qkvb_p)
{
    int v = blockIdx.x * 256 + threadIdx.x;
    if (v >= CV_S6) return;
    const float4 z4 = {0.f, 0.f, 0.f, 0.f};
    if (v < CV_S0) {
        size_t e = (size_t)v * 4;
        int row = (int)(e / DD);
        int c = (int)(e % DD);
        int l = row / D3P, lr = row % D3P;
        float4 f = z4;
        if (lr < D3)
            f = *(const float4*)(qkv_w + ((size_t)l * D3 + lr) * DD + c);
        store_bf4(w_qkv + e, f);
    } else if (v < CV_S1) {
        int e = v - CV_S0;
        store_bf4(w_proj + (size_t)e * 4, ((const float4*)proj_w)[e]);
    } else if (v < CV_S2) {
        size_t e = (size_t)(v - CV_S1) * 4;
        int row = (int)(e / DD);
        int c = (int)(e % DD);
        int l = row / MLP_P, lr = row % MLP_P;
        float4 f = z4;
        if (lr < MLP_R)
            f = *(const float4*)(fc1_w + ((size_t)l * MLP_R + lr) * DD + c);
        store_bf4(w_fc1 + e, f);
    } else if (v < CV_S3) {
        size_t e = (size_t)(v - CV_S2) * 4;
        int row = (int)(e / MLP_P);
        int c = (int)(e % MLP_P);
        float4 f = z4;
        if (c < MLP_R)
            f = *(const float4*)(fc2_w + (size_t)row * MLP_R + c);
        store_bf4(w_fc2 + e, f);
    } else if (v < CV_S4) {
        size_t e = (size_t)(v - CV_S3) * 4;
        int row = (int)(e / KP);
        int c = (int)(e % KP);
        float4 f = z4;
        if (c < 588)
            f = *(const float4*)(patch_w + (size_t)row * 588 + c);
        store_bf4(w_pat + e, f);
    } else if (v < CV_S5) {
        size_t e = (size_t)(v - CV_S4) * 4;
        int l = (int)(e / MLP_P);
        int c = (int)(e % MLP_P);
        float4 f = z4;
        if (c < MLP_R)
            f = *(const float4*)(fc1_b + (size_t)l * MLP_R + c);
        *(float4*)(fc1b_p + e) = f;
    } else {
        size_t e = (size_t)(v - CV_S5) * 4;
        int l = (int)(e / D3P);
        int c = (int)(e % D3P);
        float4 f = z4;
        if (c < D3)
            f = *(const float4*)(qkv_b + (size_t)l * D3 + c);
        *(float4*)(qkvb_p + e) = f;
    }
}

// ---------------------------------------------------------------------------
// Workspace layout (bytes)
// ---------------------------------------------------------------------------
constexpr size_t OFF_X      = 0;                                  // f32 [NT][DD]
constexpr size_t OFF_HBF    = OFF_X      + (size_t)NT * DD * 4;   // bf16 [NT][DD]
constexpr size_t OFF_TMP    = OFF_HBF    + (size_t)NT * DD * 2;   // bf16 max(NT*MLP_P, NT*NT)
constexpr size_t OFF_QKV    = OFF_TMP    + (size_t)NT * MLP_P * 2;// bf16 [NT][D3P]
constexpr size_t OFF_VT     = OFF_QKV    + (size_t)NT * D3P * 2;  // bf16 [DD][NT]
constexpr size_t OFF_IM     = OFF_VT     + (size_t)DD * NT * 2;   // bf16 [NT][KP]
constexpr size_t OFF_WQKV   = OFF_IM     + (size_t)NT * KP * 2;   // bf16 [2][D3P][DD]
constexpr size_t OFF_WPROJ  = OFF_WQKV   + (size_t)2 * D3P * DD * 2;
constexpr size_t OFF_WFC1   = OFF_WPROJ  + (size_t)2 * DD * DD * 2;   // [2][MLP_P][DD]
constexpr size_t OFF_WFC2   = OFF_WFC1   + (size_t)2 * MLP_P * DD * 2;// [2][DD][MLP_P]
constexpr size_t OFF_WPATCH = OFF_WFC2   + (size_t)2 * DD * MLP_P * 2;// [DD][KP]
constexpr size_t OFF_FC1B   = OFF_WPATCH + (size_t)DD * KP * 2;       // f32 [2][MLP_P]
constexpr size_t OFF_QKVB   = OFF_FC1B   + (size_t)2 * MLP_P * 4;     // f32 [2][D3P]

extern "C" void kernel_launch(void* const* d_in, const int* in_sizes, int n_in,
                              void* d_out, int out_size, void* d_ws, size_t ws_size,
                              hipStream_t stream)
{
    const float* img     = (const float*)d_in[0];
    const float* patch_w = (const float*)d_in[1];
    const float* patch_b = (const float*)d_in[2];
    const float* pos     = (const float*)d_in[3];
    const float* ln1_w   = (const float*)d_in[4];
    const float* ln1_b   = (const float*)d_in[5];
    const float* qkv_w   = (const float*)d_in[6];
    const float* qkv_b   = (const float*)d_in[7];
    const float* proj_w  = (const float*)d_in[8];
    const float* proj_b  = (const float*)d_in[9];
    const float* ln2_w   = (const float*)d_in[10];
    const float* ln2_b   = (const float*)d_in[11];
    const float* fc1_w   = (const float*)d_in[12];
    const float* fc1_b   = (const float*)d_in[13];
    const float* fc2_w   = (const float*)d_in[14];
    const float* fc2_b   = (const float*)d_in[15];
    const float* post_w  = (const float*)d_in[16];
    const float* post_b  = (const float*)d_in[17];

    char* ws = (char*)d_ws;
    float* x      = (float*)(ws + OFF_X);
    u16*  h_bf    = (u16*)(ws + OFF_HBF);
    u16*  tmp_bf  = (u16*)(ws + OFF_TMP);
    u16*  qkv_bf  = (u16*)(ws + OFF_QKV);
    u16*  vt      = (u16*)(ws + OFF_VT);
    u16*  a_im    = (u16*)(ws + OFF_IM);
    u16*  w_qkv   = (u16*)(ws + OFF_WQKV);
    u16*  w_proj  = (u16*)(ws + OFF_WPROJ);
    u16*  w_fc1   = (u16*)(ws + OFF_WFC1);
    u16*  w_fc2   = (u16*)(ws + OFF_WFC2);
    u16*  w_pat   = (u16*)(ws + OFF_WPATCH);
    float* fc1b_p = (float*)(ws + OFF_FC1B);
    float* qkvb_p = (float*)(ws + OFF_QKVB);

    // ---- fused weight/bias conversion (1 dispatch) + im2col ----
    convert_all<<<CV_BLOCKS, 256, 0, stream>>>(
        qkv_w, proj_w, fc1_w, fc2_w, patch_w, fc1_b, qkv_b,
        w_qkv, w_proj, w_fc1, w_fc2, w_pat, fc1b_p, qkvb_p);
    im2col_kernel<<<dim3(3, NT), 256, 0, stream>>>(img, a_im);

    // ---- patch embed: x = im2col * patch_w^T + patch_b + pos (fused T) ----
    // NTB=64: 64x18 = 1152 blocks, 4.5 blocks/CU
    gemm_bt<4, 64, 1, 64><<<1152, 256, 0, stream>>>(
        a_im, KP, w_pat, KP, KP, patch_b, pos, x, nullptr, DD, nullptr, 18);

    for (int l = 0; l < 2; ++l) {
        // LN1 -> bf16
        ln_kernel<0><<<NT, 384, 0, stream>>>(x, ln1_w + l * DD, ln1_b + l * DD, h_bf);
        // QKV = h * Wqkv^T + b  (padded N=3584: 224 blocks; fused V-transpose)
        gemm8p<1><<<224, 512, 0, stream>>>(
            h_bf, w_qkv + (size_t)l * D3P * DD, DD, DD,
            qkvb_p + (size_t)l * D3P, qkv_bf, D3P, 14, vt);
        // scores = Q K^T  (16x16 tiles = 256 blocks, single round)
        gemm8p<0><<<256, 512, 0, stream>>>(
            qkv_bf, qkv_bf + DD, D3P, DD, nullptr, tmp_bf, NT, 16, nullptr);
        // softmax rows (in place)
        softmax_kernel<<<NT, 256, 0, stream>>>(tmp_bf);
        // attn_out = P * V   (B = V^T)  NTB=64: 1152 blocks, 4.5/CU
        gemm_bt<0, 64, 1, 64><<<1152, 256, 0, stream>>>(
            tmp_bf, NT, vt, NT, NT, nullptr, nullptr, nullptr, h_bf, DD, nullptr, 18);
        // x += attn_out * Wproj^T + b
        gemm_bt<3, 64, 1, 64><<<1152, 256, 0, stream>>>(
            h_bf, DD, w_proj + (size_t)l * DD * DD, DD, DD,
            proj_b + (size_t)l * DD, x, x, nullptr, DD, nullptr, 18);
        // LN2 -> bf16
        ln_kernel<0><<<NT, 384, 0, stream>>>(x, ln2_w + l * DD, ln2_b + l * DD, h_bf);
        // h2 = gelu(h * Wfc1^T + b)  (gemm2p, 1088 blocks, m-fast decode)
        gemm2p<2><<<1088, 512, 0, stream>>>(
            h_bf, w_fc1 + (size_t)l * MLP_P * DD, DD, DD,
            fc1b_p + (size_t)l * MLP_P, nullptr, nullptr, tmp_bf, MLP_P, 34);
        // x += h2 * Wfc2^T + b
        gemm_bt<3, 64, 1, 64><<<1152, 256, 0, stream>>>(
            tmp_bf, MLP_P, w_fc2 + (size_t)l * DD * MLP_P, MLP_P, MLP_P,
            fc2_b + (size_t)l * DD, x, x, nullptr, DD, nullptr, 18);
    }
    // final LN -> f32 d_out
    ln_kernel<1><<<NT, 384, 0, stream>>>(x, post_w, post_b, d_out);
}

// Round 12
// 918.413 us; speedup vs baseline: 1.0651x; 1.0651x over previous
//
#include <hip/hip_runtime.h>

#define NT 4096
#define DD 1152
#define D3 3456
#define D3P 3584
#define MLP_R 4304
#define MLP_P 4352
#define KP 640

typedef unsigned short u16;
typedef short v8s __attribute__((ext_vector_type(8)));
typedef float v4f __attribute__((ext_vector_type(4)));

__device__ __forceinline__ u16 f2b(float f) {
    unsigned int u = __builtin_bit_cast(unsigned int, f);
    u += 0x7fffu + ((u >> 16) & 1u);          // round-to-nearest-even
    return (u16)(u >> 16);
}
__device__ __forceinline__ float b2f(u16 s) {
    unsigned int u = ((unsigned int)s) << 16;
    return __builtin_bit_cast(float, u);
}

__device__ __forceinline__ void async16(const void* g, void* l) {
    __builtin_amdgcn_global_load_lds(
        (const __attribute__((address_space(1))) void*)g,
        (__attribute__((address_space(3))) void*)l, 16, 0, 0);
}

// raw LDS byte offset of a generic pointer known to live in LDS
__device__ __forceinline__ unsigned lds_off(const void* p) {
    return (unsigned)(size_t)(const __attribute__((address_space(3))) void*)p;
}
// asm ds_read_b128: invisible to the memory legalizer, so the compiler does
// NOT insert s_waitcnt vmcnt(0) guards against outstanding global_load_lds.
// Synchronization is 100% manual (barrier + lgkmcnt + sched_barrier).
__device__ __forceinline__ v8s ldsr(unsigned byte_off) {
    v8s r;
    asm volatile("ds_read_b128 %0, %1" : "=v"(r) : "v"(byte_off));
    return r;
}

__device__ __forceinline__ float gelu_f(float t) {
    float u = t * (0.7978845608028654f + 0.03567740814183026f * t * t);
    return t / (1.0f + __expf(-2.0f * u));
}

// ---------------------------------------------------------------------------
// 128x128 2-phase GEMM, 2 blocks/CU (R8-proven: 33 us per 512-block round).
// ONLY user: FC1 (1088 blocks = 2.125 rounds). Needs >= 2 blocks/CU to win
// (R9: at 1.1 blocks/CU it loses to gemm_bt-MT64). NTB=64 probe (R11) also
// regressed: extra blocks bring proportional extra B-staging traffic — the
// ceiling is staging-bytes-per-output, not wave count.
// EPI: 2 = bf16(gelu(acc+bias))
// ---------------------------------------------------------------------------
template<int EPI>
__global__ __launch_bounds__(512, 4)
void gemm2p(const u16* __restrict__ A, const u16* __restrict__ B, int ld,
            int Kdim, const float* __restrict__ bias,
            const float* __restrict__ aux, float* __restrict__ outf,
            u16* __restrict__ outb, int ldc, int NNT)
{
    __shared__ __align__(128) union { u16 kl[2][16384]; float sc[8][64][17]; } sm;
    const int tid  = threadIdx.x, lane = tid & 63, wave = tid >> 6;
    const int wr   = wave >> 2, wc = wave & 3;
    const int fr   = lane & 15, kqh = lane >> 4;

    // XCD-compact bijective remap (nwg % 8 == 0)
    const int nwg  = gridDim.x;
    const int bidx = (int)blockIdx.x;
    const int wg   = (bidx & 7) * (nwg >> 3) + (bidx >> 3);
    const int mt   = wg / NNT, nt = wg % NNT;
    const int bm0  = mt * 128, bn0 = nt * 128;

    // 16KB-half staging involution (identical to gemm8p)
    const int c    = tid;
    const int s_lr = (c >> 7) * 16 + ((c >> 2) & 15);
    const int s_lc = ((((c >> 6) & 1) * 4) + ((c & 3) ^ (((c >> 5) & 1) << 1))) * 8;
    const size_t s_off = (size_t)s_lr * ld + s_lc;
    const unsigned koff2 = (unsigned)(fr * 64 + ((kqh * 16) ^ ((fr & 8) << 2)));

    u16* kb = sm.kl[0];
    const unsigned lbase = lds_off(kb);

    auto stage = [&](int bi, int reg, const u16* gRowBase) {
        u16* lb = kb + bi * 16384 + reg * 4096;   // reg: 0 = A half, 2 = B half
        async16(gRowBase + s_off, lb + tid * 8);
        async16(gRowBase + s_off + (size_t)64 * ld, lb + (512 + tid) * 8);
    };
    auto srcA = [&](int t) { return A + (size_t)bm0 * ld + t * 64; };
    auto srcB = [&](int t) { return B + (size_t)bn0 * ld + t * 64; };

    v4f acc[4][2];
    const v4f vzero = {0.f, 0.f, 0.f, 0.f};
#pragma unroll
    for (int i = 0; i < 4; ++i) { acc[i][0] = vzero; acc[i][1] = vzero; }

    const int NKT = Kdim >> 6;

    // ---- prologue: tile0 fully + tile1's B half; vmcnt(2) => tile0 landed
    stage(0, 0, srcA(0));
    stage(0, 2, srcB(0));
    if (NKT > 1) {
        stage(1, 2, srcB(1));
        asm volatile("s_waitcnt vmcnt(2)" ::: "memory");
    } else {
        asm volatile("s_waitcnt vmcnt(0)" ::: "memory");
    }
    __builtin_amdgcn_s_barrier();

    v8s a[8], b0f[2], b1f[2];
    for (int t = 0; t < NKT; ++t) {
        const int bi = t & 1;
        const unsigned AB = lbase + bi * 32768;
        const unsigned BB = AB + 16384;

        // ---- P1: read everything; stage A(t+1); MFMA nj=0 ----------------
#pragma unroll
        for (int mi = 0; mi < 4; ++mi)
#pragma unroll
            for (int ks = 0; ks < 2; ++ks)
                a[mi * 2 + ks] = ldsr(AB + ((wr * 4 + mi) * 2 + ks) * 1024 + koff2);
#pragma unroll
        for (int ks = 0; ks < 2; ++ks)
            b0f[ks] = ldsr(BB + ((wc * 2 + 0) * 2 + ks) * 1024 + koff2);
#pragma unroll
        for (int ks = 0; ks < 2; ++ks)
            b1f[ks] = ldsr(BB + ((wc * 2 + 1) * 2 + ks) * 1024 + koff2);
        if (t + 1 < NKT) stage(bi ^ 1, 0, srcA(t + 1));
        __builtin_amdgcn_s_barrier();
        asm volatile("s_waitcnt lgkmcnt(0)" ::: "memory");
        __builtin_amdgcn_sched_barrier(0);
        __builtin_amdgcn_s_setprio(1);
#pragma unroll
        for (int mi = 0; mi < 4; ++mi)
#pragma unroll
            for (int ks = 0; ks < 2; ++ks)
                acc[mi][0] = __builtin_amdgcn_mfma_f32_16x16x32_bf16(
                    a[mi * 2 + ks], b0f[ks], acc[mi][0], 0, 0, 0);
        __builtin_amdgcn_s_setprio(0);
        __builtin_amdgcn_s_barrier();

        // ---- P2: stage B(t+2) into bi (reads of bi done); MFMA nj=1 ------
        if (t + 2 < NKT) stage(bi, 2, srcB(t + 2));
        __builtin_amdgcn_s_setprio(1);
#pragma unroll
        for (int mi = 0; mi < 4; ++mi)
#pragma unroll
            for (int ks = 0; ks < 2; ++ks)
                acc[mi][1] = __builtin_amdgcn_mfma_f32_16x16x32_bf16(
                    a[mi * 2 + ks], b1f[ks], acc[mi][1], 0, 0, 0);
        __builtin_amdgcn_s_setprio(0);
        if (t + 2 < NKT) { asm volatile("s_waitcnt vmcnt(2)" ::: "memory"); }
        else             { asm volatile("s_waitcnt vmcnt(0)" ::: "memory"); }
        __builtin_amdgcn_s_barrier();
    }

    // ---- epilogue: gemm_bt-style LDS transpose, JT=2 ---------------------
    const int cn = lane & 15;
    const int cm = (lane >> 4) * 4;
    float (*S)[17] = sm.sc[wave];
    const int gm = bm0 + wr * 64 + lane;
#pragma unroll
    for (int jp = 0; jp < 2; ++jp) {
        __syncthreads();
#pragma unroll
        for (int i = 0; i < 4; ++i)
#pragma unroll
            for (int r = 0; r < 4; ++r)
                S[i * 16 + cm + r][cn] = acc[i][jp][r];
        __syncthreads();
        const int gn0 = bn0 + wc * 32 + jp * 16;
        float v[16];
#pragma unroll
        for (int cc = 0; cc < 16; ++cc) v[cc] = S[lane][cc];
        union { u16 us[16]; uint4 q4[2]; } o;
#pragma unroll
        for (int cc = 0; cc < 16; ++cc) {
            float tv = v[cc];
            if constexpr (EPI >= 1) tv += bias[gn0 + cc];
            if constexpr (EPI == 2) tv = gelu_f(tv);
            o.us[cc] = f2b(tv);
        }
        uint4* dst = (uint4*)(outb + (size_t)gm * ldc + gn0);
        dst[0] = o.q4[0];
        dst[1] = o.q4[1];
    }
}

// ---------------------------------------------------------------------------
// 256x256 8-phase GEMM — round-4 schedule (proven). 1 block/CU; best for
// grids <= 256 blocks (single round). Used by QKV (224) and QKT (256).
// EPI: 0 = bf16 out; 1 = bf16(acc+bias) + fused V-transpose; 2 = gelu
// ---------------------------------------------------------------------------
template<int EPI>
__global__ __launch_bounds__(512, 2)
void gemm8p(const u16* __restrict__ A, const u16* __restrict__ B, int ld,
            int Kdim, const float* __restrict__ bias,
            u16* __restrict__ outb, int ldc, int NNT, u16* __restrict__ vt)
{
    __shared__ __align__(128) union { u16 kl[2][32768]; u16 ep[8][8192]; } sm;
    const int tid  = threadIdx.x, lane = tid & 63, wave = tid >> 6;
    const int wr   = wave >> 2, wc = wave & 3;
    const int fr   = lane & 15, kqh = lane >> 4;

    const int nwg  = gridDim.x;
    const int bidx = (int)blockIdx.x;
    const int wg   = (bidx & 7) * (nwg >> 3) + (bidx >> 3);
    const int mt   = wg / NNT, nt = wg % NNT;
    const int bm0  = mt * 256, bn0 = nt * 256;

    const int c    = tid;
    const int s_lr = (c >> 7) * 16 + ((c >> 2) & 15);
    const int s_lc = ((((c >> 6) & 1) * 4) + ((c & 3) ^ (((c >> 5) & 1) << 1))) * 8;
    const size_t s_off = (size_t)s_lr * ld + s_lc;
    const unsigned koff2 = (unsigned)(fr * 64 + ((kqh * 16) ^ ((fr & 8) << 2)));

    u16* kb = sm.kl[0];
    const unsigned lbase = lds_off(kb);

    auto stage = [&](int bi, int reg, const u16* gRowBase) {
        u16* lb = kb + bi * 32768 + reg * 4096;
        async16(gRowBase + s_off, lb + tid * 8);
        async16(gRowBase + s_off + (size_t)64 * ld, lb + (512 + tid) * 8);
    };
    auto srcA = [&](int h, int t) { return A + (size_t)(bm0 + h * 128) * ld + t * 64; };
    auto srcB = [&](int h, int t) { return B + (size_t)(bn0 + h * 128) * ld + t * 64; };

    v4f acc[8][4];
    const v4f vzero = {0.f, 0.f, 0.f, 0.f};
#pragma unroll
    for (int i = 0; i < 8; ++i)
#pragma unroll
        for (int j = 0; j < 4; ++j) acc[i][j] = vzero;

    const int NKT = Kdim >> 6;

    stage(0, 4, srcB(0, 0));
    stage(0, 6, srcB(1, 0));
    stage(0, 0, srcA(0, 0));
    stage(0, 2, srcA(1, 0));
    if (NKT > 1) {
        stage(1, 4, srcB(0, 1));
        stage(1, 6, srcB(1, 1));
        asm volatile("s_waitcnt vmcnt(4)" ::: "memory");
    } else {
        asm volatile("s_waitcnt vmcnt(0)" ::: "memory");
    }
    __builtin_amdgcn_s_barrier();

    v8s a[8], b0f[4], b1f[4];
    for (int t = 0; t < NKT; ++t) {
        const int bi = t & 1;
        const unsigned AB = lbase + bi * 65536 + wr * 16384;
        const unsigned BB = lbase + bi * 65536 + 32768 + (wc >> 1) * 16384;
        const unsigned bs = (wc & 1) * 8192;

        // phase 1
#pragma unroll
        for (int mi = 0; mi < 4; ++mi)
#pragma unroll
            for (int ks = 0; ks < 2; ++ks)
                a[mi * 2 + ks] = ldsr(AB + (mi * 2 + ks) * 1024 + koff2);
#pragma unroll
        for (int nj = 0; nj < 2; ++nj)
#pragma unroll
            for (int ks = 0; ks < 2; ++ks)
                b0f[nj * 2 + ks] = ldsr(BB + bs + (nj * 2 + ks) * 1024 + koff2);
        if (t + 1 < NKT) stage(bi ^ 1, 0, srcA(0, t + 1));
        __builtin_amdgcn_s_barrier();
        asm volatile("s_waitcnt lgkmcnt(0)" ::: "memory");
        __builtin_amdgcn_sched_barrier(0);
        __builtin_amdgcn_s_setprio(1);
#pragma unroll
        for (int mi = 0; mi < 4; ++mi)
#pragma unroll
            for (int nj = 0; nj < 2; ++nj)
#pragma unroll
                for (int ks = 0; ks < 2; ++ks)
                    acc[mi][nj] = __builtin_amdgcn_mfma_f32_16x16x32_bf16(
                        a[mi * 2 + ks], b0f[nj * 2 + ks], acc[mi][nj], 0, 0, 0);
        __builtin_amdgcn_s_setprio(0);
        __builtin_amdgcn_s_barrier();

        // phase 2
#pragma unroll
        for (int nj = 0; nj < 2; ++nj)
#pragma unroll
            for (int ks = 0; ks < 2; ++ks)
                b1f[nj * 2 + ks] = ldsr(BB + bs + (4 + nj * 2 + ks) * 1024 + koff2);
        if (t + 1 < NKT) stage(bi ^ 1, 2, srcA(1, t + 1));
        __builtin_amdgcn_s_barrier();
        asm volatile("s_waitcnt lgkmcnt(0)" ::: "memory");
        __builtin_amdgcn_sched_barrier(0);
        __builtin_amdgcn_s_setprio(1);
#pragma unroll
        for (int mi = 0; mi < 4; ++mi)
#pragma unroll
            for (int nj = 0; nj < 2; ++nj)
#pragma unroll
                for (int ks = 0; ks < 2; ++ks)
                    acc[mi][2 + nj] = __builtin_amdgcn_mfma_f32_16x16x32_bf16(
                        a[mi * 2 + ks], b1f[nj * 2 + ks], acc[mi][2 + nj], 0, 0, 0);
        __builtin_amdgcn_s_setprio(0);
        __builtin_amdgcn_s_barrier();

        // phase 3
#pragma unroll
        for (int mi = 0; mi < 4; ++mi)
#pragma unroll
            for (int ks = 0; ks < 2; ++ks)
                a[mi * 2 + ks] = ldsr(AB + (8 + mi * 2 + ks) * 1024 + koff2);
        if (t + 2 < NKT) stage(bi, 4, srcB(0, t + 2));
        __builtin_amdgcn_s_barrier();
        asm volatile("s_waitcnt lgkmcnt(0)" ::: "memory");
        __builtin_amdgcn_sched_barrier(0);
        __builtin_amdgcn_s_setprio(1);
#pragma unroll
        for (int mi = 0; mi < 4; ++mi)
#pragma unroll
            for (int nj = 0; nj < 2; ++nj)
#pragma unroll
                for (int ks = 0; ks < 2; ++ks)
                    acc[4 + mi][2 + nj] = __builtin_amdgcn_mfma_f32_16x16x32_bf16(
                        a[mi * 2 + ks], b1f[nj * 2 + ks], acc[4 + mi][2 + nj], 0, 0, 0);
        __builtin_amdgcn_s_setprio(0);
        __builtin_amdgcn_s_barrier();

        // phase 4
        if (t + 2 < NKT) stage(bi, 6, srcB(1, t + 2));
        __builtin_amdgcn_s_barrier();
        __builtin_amdgcn_s_setprio(1);
#pragma unroll
        for (int mi = 0; mi < 4; ++mi)
#pragma unroll
            for (int nj = 0; nj < 2; ++nj)
#pragma unroll
                for (int ks = 0; ks < 2; ++ks)
                    acc[4 + mi][nj] = __builtin_amdgcn_mfma_f32_16x16x32_bf16(
                        a[mi * 2 + ks], b0f[nj * 2 + ks], acc[4 + mi][nj], 0, 0, 0);
        __builtin_amdgcn_s_setprio(0);
        if (t + 2 < NKT) { asm volatile("s_waitcnt vmcnt(4)" ::: "memory"); }
        else             { asm volatile("s_waitcnt vmcnt(0)" ::: "memory"); }
        __builtin_amdgcn_s_barrier();
    }

    asm volatile("s_waitcnt vmcnt(0)" ::: "memory");
    __builtin_amdgcn_s_barrier();
    u16* ew = sm.ep[wave];
    float bcol[4];
    if constexpr (EPI >= 1) {
#pragma unroll
        for (int nj = 0; nj < 4; ++nj)
            bcol[nj] = bias[bn0 + wc * 64 + nj * 16 + fr];
    }
#pragma unroll
    for (int mi = 0; mi < 8; ++mi)
#pragma unroll
        for (int nj = 0; nj < 4; ++nj)
#pragma unroll
            for (int r = 0; r < 4; ++r) {
                int row = mi * 16 + kqh * 4 + r;
                int ec  = nj * 16 + fr;
                float t = acc[mi][nj][r];
                if constexpr (EPI >= 1) t += bcol[nj];
                if constexpr (EPI == 2) t = gelu_f(t);
                ew[row * 64 + (ec ^ (((row >> 2) & 3) << 4))] = f2b(t);
            }
    __syncthreads();
    const int gc = bn0 + wc * 64 + (lane & 7) * 8;
    const bool inV = (EPI == 1) && (vt != nullptr) && gc >= 2304 && gc < D3;
#pragma unroll
    for (int p = 0; p < 16; ++p) {
        int row = p * 8 + (lane >> 3);
        int key = (row >> 2) & 3;
        v8s ch = *(const v8s*)(ew + row * 64 + (((lane & 7) * 8) ^ (key << 4)));
        size_t gm = (size_t)(bm0 + wr * 128 + row);
        *(uint4*)(outb + gm * ldc + gc) = __builtin_bit_cast(uint4, ch);
        if constexpr (EPI == 1) {
            if (inV) {
                union { v8s v; u16 us[8]; } cu; cu.v = ch;
#pragma unroll
                for (int j = 0; j < 8; ++j)
                    vt[(size_t)(gc + j - 2304) * NT + gm] = cu.us[j];
            }
        }
    }
}

// ---------------------------------------------------------------------------
// GEMM: C[m][n] = sum_k A[m][k] * B[n][k]   (B transposed, K contiguous)
// DBUF=1 (MT=64): double-buffered LDS, one barrier per K-step. Proven best
// for the N=1152 family (576 blocks = 2.25 blocks/CU at 48KB LDS).
// R11 NTB=64 probe regressed (FETCH +16%, dur 70->85); 128-wide N-tile kept.
// EPI: 0 = bf16 out; 2 = bf16(gelu(acc+bias)); 3 = f32 out = aux + acc + bias;
//      4 = f32 out = acc + bias[n] + pos[n][m]  (aux = pos, [D][NT] layout)
// ---------------------------------------------------------------------------
template<int EPI, int MT, int DBUF = 0>
__global__ __launch_bounds__(256)
void gemm_bt(const u16* __restrict__ A, int lda,
             const u16* __restrict__ B, int ldb, int Kdim,
             const float* __restrict__ bias, const float* __restrict__ aux,
             float* __restrict__ outf, u16* __restrict__ outb, int ldc,
             u16* __restrict__ vt, int NX)
{
    constexpr int JT = (MT == 128) ? 4 : 2;
    constexpr int AR = MT * 8 / 256;
    constexpr int NB = DBUF ? 2 : 1;

    __shared__ union SM {
        struct { u16 a[NB * MT * 64]; u16 b[NB * 128 * 64]; } st;
        float sc[4][64][17];
    } sm;

    const int b    = blockIdx.x;
    const int MY   = (gridDim.x >> 3) / NX;
    const int q    = b >> 3;
    const int m0   = ((b & 7) * MY + q % MY) * MT;
    const int n0   = (q / MY) * 128;

    const int tid  = threadIdx.x;
    const int lane = tid & 63;
    const int wave = tid >> 6;
    const int wm   = (MT == 128) ? (wave & 1) * 64 : 0;
    const int wn   = (MT == 128) ? (wave >> 1) * 64 : wave * 32;
    const int fr   = lane & 15;
    const int kqh  = lane >> 4;
    const int swz  = fr & 7;

    v4f acc[4][JT];
    const v4f vzero = {0.f, 0.f, 0.f, 0.f};
#pragma unroll
    for (int i = 0; i < 4; ++i)
#pragma unroll
        for (int j = 0; j < JT; ++j) acc[i][j] = vzero;

    auto stage = [&](u16* As, u16* Bs, int kt) {
#pragma unroll
        for (int r = 0; r < AR; ++r) {
            int c = r * 256 + tid;
            int row = c >> 3;
            int kc = (c & 7) ^ (row & 7);
            async16(A + (size_t)(m0 + row) * lda + kt + kc * 8, As + c * 8);
        }
#pragma unroll
        for (int r = 0; r < 4; ++r) {
            int c = r * 256 + tid;
            int row = c >> 3;
            int kc = (c & 7) ^ (row & 7);
            async16(B + (size_t)(n0 + row) * ldb + kt + kc * 8, Bs + c * 8);
        }
    };

    auto compute = [&](const u16* As, const u16* Bs) {
#pragma unroll
        for (int ks = 0; ks < 2; ++ks) {
            const int kq = ks * 4 + kqh;
            const int kp = (kq ^ swz) * 8;
            v8s af[4], bf[JT];
#pragma unroll
            for (int i = 0; i < 4; ++i)
                af[i] = *(const v8s*)(As + (wm + i * 16 + fr) * 64 + kp);
#pragma unroll
            for (int j = 0; j < JT; ++j)
                bf[j] = *(const v8s*)(Bs + (wn + j * 16 + fr) * 64 + kp);
#pragma unroll
            for (int i = 0; i < 4; ++i)
#pragma unroll
                for (int j = 0; j < JT; ++j)
                    acc[i][j] = __builtin_amdgcn_mfma_f32_16x16x32_bf16(
                        af[i], bf[j], acc[i][j], 0, 0, 0);
        }
    };

    if constexpr (DBUF) {
        stage(sm.st.a, sm.st.b, 0);
        int cur = 0;
        for (int kt = 0; kt < Kdim; kt += 64) {
            __syncthreads();
            const int nxt = cur ^ 1;
            if (kt + 64 < Kdim)
                stage(sm.st.a + nxt * (MT * 64), sm.st.b + nxt * (128 * 64), kt + 64);
            compute(sm.st.a + cur * (MT * 64), sm.st.b + cur * (128 * 64));
            cur = nxt;
        }
    } else {
        for (int kt = 0; kt < Kdim; kt += 64) {
            stage(sm.st.a, sm.st.b, kt);
            __syncthreads();
            compute(sm.st.a, sm.st.b);
            __syncthreads();
        }
    }

    const int cn = lane & 15;
    const int cm = (lane >> 4) * 4;
    float (*S)[17] = sm.sc[wave];
    const int gm = m0 + wm + lane;
#pragma unroll
    for (int jp = 0; jp < JT; ++jp) {
        __syncthreads();
#pragma unroll
        for (int i = 0; i < 4; ++i)
#pragma unroll
            for (int r = 0; r < 4; ++r)
                S[i * 16 + cm + r][cn] = acc[i][jp][r];
        __syncthreads();
        const int gn0 = n0 + wn + jp * 16;
        float v[16];
#pragma unroll
        for (int c = 0; c < 16; ++c) v[c] = S[lane][c];
        if constexpr (EPI <= 2) {
            union { u16 us[16]; uint4 q4[2]; } o;
#pragma unroll
            for (int c = 0; c < 16; ++c) {
                float t = v[c];
                if constexpr (EPI >= 1) t += bias[gn0 + c];
                if constexpr (EPI == 2) t = gelu_f(t);
                o.us[c] = f2b(t);
            }
            uint4* dst = (uint4*)(outb + (size_t)gm * ldc + gn0);
            dst[0] = o.q4[0];
            dst[1] = o.q4[1];
            if constexpr (EPI == 1) {
                if (vt != nullptr && gn0 >= 2304) {
#pragma unroll
                    for (int c = 0; c < 16; ++c)
                        vt[(size_t)(gn0 + c - 2304) * NT + gm] = o.us[c];
                }
            }
        } else if constexpr (EPI == 3) {
            float* dst = outf + (size_t)gm * ldc + gn0;
            const float* ax = aux + (size_t)gm * ldc + gn0;
#pragma unroll
            for (int c = 0; c < 4; ++c) {
                float4 a4 = ((const float4*)ax)[c];
                float4 r4;
                r4.x = a4.x + v[4 * c + 0] + bias[gn0 + 4 * c + 0];
                r4.y = a4.y + v[4 * c + 1] + bias[gn0 + 4 * c + 1];
                r4.z = a4.z + v[4 * c + 2] + bias[gn0 + 4 * c + 2];
                r4.w = a4.w + v[4 * c + 3] + bias[gn0 + 4 * c + 3];
                ((float4*)dst)[c] = r4;
            }
        } else {
            float* dst = outf + (size_t)gm * ldc + gn0;
#pragma unroll
            for (int c = 0; c < 4; ++c) {
                float4 r4;
                r4.x = v[4 * c + 0] + bias[gn0 + 4 * c + 0] + aux[(size_t)(gn0 + 4 * c + 0) * NT + gm];
                r4.y = v[4 * c + 1] + bias[gn0 + 4 * c + 1] + aux[(size_t)(gn0 + 4 * c + 1) * NT + gm];
                r4.z = v[4 * c + 2] + bias[gn0 + 4 * c + 2] + aux[(size_t)(gn0 + 4 * c + 2) * NT + gm];
                r4.w = v[4 * c + 3] + bias[gn0 + 4 * c + 3] + aux[(size_t)(gn0 + 4 * c + 3) * NT + gm];
                ((float4*)dst)[c] = r4;
            }
        }
    }
}

// ---------------------------------------------------------------------------
// LayerNorm over D=1152. 384 threads, 3 elems each. OUTF=1 -> f32, else bf16.
// ---------------------------------------------------------------------------
template<int OUTF>
__global__ __launch_bounds__(384)
void ln_kernel(const float* __restrict__ x, const float* __restrict__ w,
               const float* __restrict__ b, void* __restrict__ out)
{
    const int n = blockIdx.x;
    const int t = threadIdx.x;
    const float* row = x + (size_t)n * DD;
    float v0 = row[t], v1 = row[t + 384], v2 = row[t + 768];
    float s  = v0 + v1 + v2;
    float ss = v0 * v0 + v1 * v1 + v2 * v2;
#pragma unroll
    for (int o = 32; o > 0; o >>= 1) {
        s  += __shfl_down(s, o);
        ss += __shfl_down(ss, o);
    }
    __shared__ float ps[6], pss[6], mh[2];
    if ((t & 63) == 0) { ps[t >> 6] = s; pss[t >> 6] = ss; }
    __syncthreads();
    if (t == 0) {
        float S = 0.f, SS = 0.f;
        for (int i = 0; i < 6; ++i) { S += ps[i]; SS += pss[i]; }
        float m = S / (float)DD;
        float var = SS / (float)DD - m * m;
        mh[0] = m;
        mh[1] = rsqrtf(var + 1e-6f);
    }
    __syncthreads();
    const float m = mh[0], rs = mh[1];
#pragma unroll
    for (int j = 0; j < 3; ++j) {
        int c = t + j * 384;
        float y = (row[c] - m) * rs * w[c] + b[c];
        if constexpr (OUTF) ((float*)out)[(size_t)n * DD + c] = y;
        else                ((u16*)out)[(size_t)n * DD + c]   = f2b(y);
    }
}

// ---------------------------------------------------------------------------
// Softmax over rows of bf16 scores [NT x NT], in place, with scale.
// ---------------------------------------------------------------------------
__global__ __launch_bounds__(256)
void softmax_kernel(u16* __restrict__ s)
{
    const float SC = 0.029462782549439484f;  // 1/sqrt(1152)
    const int row = blockIdx.x;
    const int t = threadIdx.x;
    u16* p = s + (size_t)row * NT + t * 16;
    uint4 u0 = *(const uint4*)p;
    uint4 u1 = *(const uint4*)(p + 8);
    float v[16];
    unsigned int w[8] = {u0.x, u0.y, u0.z, u0.w, u1.x, u1.y, u1.z, u1.w};
#pragma unroll
    for (int i = 0; i < 8; ++i) {
        v[2 * i]     = b2f((u16)(w[i] & 0xffffu)) * SC;
        v[2 * i + 1] = b2f((u16)(w[i] >> 16)) * SC;
    }
    float mx = -1e30f;
#pragma unroll
    for (int i = 0; i < 16; ++i) mx = fmaxf(mx, v[i]);
#pragma unroll
    for (int o = 32; o > 0; o >>= 1) mx = fmaxf(mx, __shfl_down(mx, o));
    __shared__ float red[4];
    __shared__ float bc;
    if ((t & 63) == 0) red[t >> 6] = mx;
    __syncthreads();
    if (t == 0) bc = fmaxf(fmaxf(red[0], red[1]), fmaxf(red[2], red[3]));
    __syncthreads();
    const float M = bc;
    float sum = 0.f;
#pragma unroll
    for (int i = 0; i < 16; ++i) { v[i] = __expf(v[i] - M); sum += v[i]; }
#pragma unroll
    for (int o = 32; o > 0; o >>= 1) sum += __shfl_down(sum, o);
    __syncthreads();
    if ((t & 63) == 0) red[t >> 6] = sum;
    __syncthreads();
    if (t == 0) bc = red[0] + red[1] + red[2] + red[3];
    __syncthreads();
    const float inv = 1.0f / bc;
    union { u16 us[8]; uint4 u4; } o0, o1;
#pragma unroll
    for (int i = 0; i < 8; ++i) o0.us[i] = f2b(v[i] * inv);
#pragma unroll
    for (int i = 0; i < 8; ++i) o1.us[i] = f2b(v[8 + i] * inv);
    *(uint4*)p = o0.u4;
    *(uint4*)(p + 8) = o1.u4;
}

// ---------------------------------------------------------------------------
// im2col: img [3][896][896] -> a [NT][KP] bf16 (k = cin*196+py*14+px, pad->0)
// ---------------------------------------------------------------------------
__global__ __launch_bounds__(256)
void im2col_kernel(const float* __restrict__ img, u16* __restrict__ a)
{
    const int k = blockIdx.x * 256 + threadIdx.x;
    const int n = blockIdx.y;
    if (k >= KP) return;
    float v = 0.f;
    if (k < 588) {
        int cin = k / 196;
        int rr = k - cin * 196;
        int py = rr / 14;
        int px = rr - py * 14;
        int gy = (n >> 6) * 14 + py;
        int gx = (n & 63) * 14 + px;
        v = img[(size_t)cin * 896 * 896 + (size_t)gy * 896 + gx];
    }
    a[(size_t)n * KP + k] = f2b(v);
}

// ---------------------------------------------------------------------------
// One fused, float4-vectorized weight conversion/pad kernel.
// QKV weights/bias PADDED to D3P=3584 rows (zeros beyond 3456).
// ---------------------------------------------------------------------------
constexpr int CV_S0 = 2 * D3P * DD / 4;
constexpr int CV_S1 = CV_S0 + 2 * DD * DD / 4;
constexpr int CV_S2 = CV_S1 + 2 * MLP_P * DD / 4;
constexpr int CV_S3 = CV_S2 + 2 * DD * MLP_P / 4;
constexpr int CV_S4 = CV_S3 + DD * KP / 4;
constexpr int CV_S5 = CV_S4 + 2 * MLP_P / 4;
constexpr int CV_S6 = CV_S5 + 2 * D3P / 4;
constexpr int CV_BLOCKS = (CV_S6 + 255) / 256;

__device__ __forceinline__ void store_bf4(u16* p, float4 f) {
    union { u16 s[4]; uint2 d; } o;
    o.s[0] = f2b(f.x); o.s[1] = f2b(f.y); o.s[2] = f2b(f.z); o.s[3] = f2b(f.w);
    *(uint2*)p = o.d;
}

__global__ __launch_bounds__(256)
void convert_all(const float* __restrict__ qkv_w, const float* __restrict__ proj_w,
                 const float* __restrict__ fc1_w, const float* __restrict__ fc2_w,
                 const float* __restrict__ patch_w, const float* __restrict__ fc1_b,
                 const float* __restrict__ qkv_b,
                 u16* __restrict__ w_qkv, u16* __restrict__ w_proj,
                 u16* __restrict__ w_fc1, u16* __restrict__ w_fc2,
                 u16* __restrict__ w_pat, float* __restrict__ fc1b_p,
                 float* __restrict__ qkvb_p)
{
    int v = blockIdx.x * 256 + threadIdx.x;
    if (v >= CV_S6) return;
    const float4 z4 = {0.f, 0.f, 0.f, 0.f};
    if (v < CV_S0) {
        size_t e = (size_t)v * 4;
        int row = (int)(e / DD);
        int c = (int)(e % DD);
        int l = row / D3P, lr = row % D3P;
        float4 f = z4;
        if (lr < D3)
            f = *(const float4*)(qkv_w + ((size_t)l * D3 + lr) * DD + c);
        store_bf4(w_qkv + e, f);
    } else if (v < CV_S1) {
        int e = v - CV_S0;
        store_bf4(w_proj + (size_t)e * 4, ((const float4*)proj_w)[e]);
    } else if (v < CV_S2) {
        size_t e = (size_t)(v - CV_S1) * 4;
        int row = (int)(e / DD);
        int c = (int)(e % DD);
        int l = row / MLP_P, lr = row % MLP_P;
        float4 f = z4;
        if (lr < MLP_R)
            f = *(const float4*)(fc1_w + ((size_t)l * MLP_R + lr) * DD + c);
        store_bf4(w_fc1 + e, f);
    } else if (v < CV_S3) {
        size_t e = (size_t)(v - CV_S2) * 4;
        int row = (int)(e / MLP_P);
        int c = (int)(e % MLP_P);
        float4 f = z4;
        if (c < MLP_R)
            f = *(const float4*)(fc2_w + (size_t)row * MLP_R + c);
        store_bf4(w_fc2 + e, f);
    } else if (v < CV_S4) {
        size_t e = (size_t)(v - CV_S3) * 4;
        int row = (int)(e / KP);
        int c = (int)(e % KP);
        float4 f = z4;
        if (c < 588)
            f = *(const float4*)(patch_w + (size_t)row * 588 + c);
        store_bf4(w_pat + e, f);
    } else if (v < CV_S5) {
        size_t e = (size_t)(v - CV_S4) * 4;
        int l = (int)(e / MLP_P);
        int c = (int)(e % MLP_P);
        float4 f = z4;
        if (c < MLP_R)
            f = *(const float4*)(fc1_b + (size_t)l * MLP_R + c);
        *(float4*)(fc1b_p + e) = f;
    } else {
        size_t e = (size_t)(v - CV_S5) * 4;
        int l = (int)(e / D3P);
        int c = (int)(e % D3P);
        float4 f = z4;
        if (c < D3)
            f = *(const float4*)(qkv_b + (size_t)l * D3 + c);
        *(float4*)(qkvb_p + e) = f;
    }
}

// ---------------------------------------------------------------------------
// Workspace layout (bytes)
// ---------------------------------------------------------------------------
constexpr size_t OFF_X      = 0;                                  // f32 [NT][DD]
constexpr size_t OFF_HBF    = OFF_X      + (size_t)NT * DD * 4;   // bf16 [NT][DD]
constexpr size_t OFF_TMP    = OFF_HBF    + (size_t)NT * DD * 2;   // bf16 max(NT*MLP_P, NT*NT)
constexpr size_t OFF_QKV    = OFF_TMP    + (size_t)NT * MLP_P * 2;// bf16 [NT][D3P]
constexpr size_t OFF_VT     = OFF_QKV    + (size_t)NT * D3P * 2;  // bf16 [DD][NT]
constexpr size_t OFF_IM     = OFF_VT     + (size_t)DD * NT * 2;   // bf16 [NT][KP]
constexpr size_t OFF_WQKV   = OFF_IM     + (size_t)NT * KP * 2;   // bf16 [2][D3P][DD]
constexpr size_t OFF_WPROJ  = OFF_WQKV   + (size_t)2 * D3P * DD * 2;
constexpr size_t OFF_WFC1   = OFF_WPROJ  + (size_t)2 * DD * DD * 2;   // [2][MLP_P][DD]
constexpr size_t OFF_WFC2   = OFF_WFC1   + (size_t)2 * MLP_P * DD * 2;// [2][DD][MLP_P]
constexpr size_t OFF_WPATCH = OFF_WFC2   + (size_t)2 * DD * MLP_P * 2;// [DD][KP]
constexpr size_t OFF_FC1B   = OFF_WPATCH + (size_t)DD * KP * 2;       // f32 [2][MLP_P]
constexpr size_t OFF_QKVB   = OFF_FC1B   + (size_t)2 * MLP_P * 4;     // f32 [2][D3P]

extern "C" void kernel_launch(void* const* d_in, const int* in_sizes, int n_in,
                              void* d_out, int out_size, void* d_ws, size_t ws_size,
                              hipStream_t stream)
{
    const float* img     = (const float*)d_in[0];
    const float* patch_w = (const float*)d_in[1];
    const float* patch_b = (const float*)d_in[2];
    const float* pos     = (const float*)d_in[3];
    const float* ln1_w   = (const float*)d_in[4];
    const float* ln1_b   = (const float*)d_in[5];
    const float* qkv_w   = (const float*)d_in[6];
    const float* qkv_b   = (const float*)d_in[7];
    const float* proj_w  = (const float*)d_in[8];
    const float* proj_b  = (const float*)d_in[9];
    const float* ln2_w   = (const float*)d_in[10];
    const float* ln2_b   = (const float*)d_in[11];
    const float* fc1_w   = (const float*)d_in[12];
    const float* fc1_b   = (const float*)d_in[13];
    const float* fc2_w   = (const float*)d_in[14];
    const float* fc2_b   = (const float*)d_in[15];
    const float* post_w  = (const float*)d_in[16];
    const float* post_b  = (const float*)d_in[17];

    char* ws = (char*)d_ws;
    float* x      = (float*)(ws + OFF_X);
    u16*  h_bf    = (u16*)(ws + OFF_HBF);
    u16*  tmp_bf  = (u16*)(ws + OFF_TMP);
    u16*  qkv_bf  = (u16*)(ws + OFF_QKV);
    u16*  vt      = (u16*)(ws + OFF_VT);
    u16*  a_im    = (u16*)(ws + OFF_IM);
    u16*  w_qkv   = (u16*)(ws + OFF_WQKV);
    u16*  w_proj  = (u16*)(ws + OFF_WPROJ);
    u16*  w_fc1   = (u16*)(ws + OFF_WFC1);
    u16*  w_fc2   = (u16*)(ws + OFF_WFC2);
    u16*  w_pat   = (u16*)(ws + OFF_WPATCH);
    float* fc1b_p = (float*)(ws + OFF_FC1B);
    float* qkvb_p = (float*)(ws + OFF_QKVB);

    // ---- fused weight/bias conversion (1 dispatch) + im2col ----
    convert_all<<<CV_BLOCKS, 256, 0, stream>>>(
        qkv_w, proj_w, fc1_w, fc2_w, patch_w, fc1_b, qkv_b,
        w_qkv, w_proj, w_fc1, w_fc2, w_pat, fc1b_p, qkvb_p);
    im2col_kernel<<<dim3(3, NT), 256, 0, stream>>>(img, a_im);

    // ---- patch embed: x = im2col * patch_w^T + patch_b + pos (fused T) ----
    gemm_bt<4, 64, 1><<<9 * 64, 256, 0, stream>>>(
        a_im, KP, w_pat, KP, KP, patch_b, pos, x, nullptr, DD, nullptr, 9);

    for (int l = 0; l < 2; ++l) {
        // LN1 -> bf16
        ln_kernel<0><<<NT, 384, 0, stream>>>(x, ln1_w + l * DD, ln1_b + l * DD, h_bf);
        // QKV = h * Wqkv^T + b  (padded N=3584: 224 blocks; fused V-transpose)
        gemm8p<1><<<224, 512, 0, stream>>>(
            h_bf, w_qkv + (size_t)l * D3P * DD, DD, DD,
            qkvb_p + (size_t)l * D3P, qkv_bf, D3P, 14, vt);
        // scores = Q K^T  (16x16 tiles = 256 blocks, single round)
        gemm8p<0><<<256, 512, 0, stream>>>(
            qkv_bf, qkv_bf + DD, D3P, DD, nullptr, tmp_bf, NT, 16, nullptr);
        // softmax rows (in place)
        softmax_kernel<<<NT, 256, 0, stream>>>(tmp_bf);
        // attn_out = P * V   (B = V^T)
        gemm_bt<0, 64, 1><<<9 * 64, 256, 0, stream>>>(
            tmp_bf, NT, vt, NT, NT, nullptr, nullptr, nullptr, h_bf, DD, nullptr, 9);
        // x += attn_out * Wproj^T + b
        gemm_bt<3, 64, 1><<<9 * 64, 256, 0, stream>>>(
            h_bf, DD, w_proj + (size_t)l * DD * DD, DD, DD,
            proj_b + (size_t)l * DD, x, x, nullptr, DD, nullptr, 9);
        // LN2 -> bf16
        ln_kernel<0><<<NT, 384, 0, stream>>>(x, ln2_w + l * DD, ln2_b + l * DD, h_bf);
        // h2 = gelu(h * Wfc1^T + b)  (gemm2p, 1088 blocks, 2 blocks/CU)
        gemm2p<2><<<1088, 512, 0, stream>>>(
            h_bf, w_fc1 + (size_t)l * MLP_P * DD, DD, DD,
            fc1b_p + (size_t)l * MLP_P, nullptr, nullptr, tmp_bf, MLP_P, 34);
        // x += h2 * Wfc2^T + b
        gemm_bt<3, 64, 1><<<9 * 64, 256, 0, stream>>>(
            tmp_bf, MLP_P, w_fc2 + (size_t)l * DD * MLP_P, MLP_P, MLP_P,
            fc2_b + (size_t)l * DD, x, x, nullptr, DD, nullptr, 9);
    }
    // final LN -> f32 d_out
    ln_kernel<1><<<NT, 384, 0, stream>>>(x, post_w, post_b, d_out);
}

// Round 13
// 864.319 us; speedup vs baseline: 1.1317x; 1.0626x over previous
//
#include <hip/hip_runtime.h>

#define NT 4096
#define DD 1152
#define D3 3456
#define D3P 3584
#define MLP_R 4304
#define MLP_P 4352
#define KP 640

typedef unsigned short u16;
typedef short v8s __attribute__((ext_vector_type(8)));
typedef float v4f __attribute__((ext_vector_type(4)));

__device__ __forceinline__ u16 f2b(float f) {
    unsigned int u = __builtin_bit_cast(unsigned int, f);
    u += 0x7fffu + ((u >> 16) & 1u);          // round-to-nearest-even
    return (u16)(u >> 16);
}
__device__ __forceinline__ float b2f(u16 s) {
    unsigned int u = ((unsigned int)s) << 16;
    return __builtin_bit_cast(float, u);
}

__device__ __forceinline__ void async16(const void* g, void* l) {
    __builtin_amdgcn_global_load_lds(
        (const __attribute__((address_space(1))) void*)g,
        (__attribute__((address_space(3))) void*)l, 16, 0, 0);
}

// raw LDS byte offset of a generic pointer known to live in LDS
__device__ __forceinline__ unsigned lds_off(const void* p) {
    return (unsigned)(size_t)(const __attribute__((address_space(3))) void*)p;
}
// asm ds_read_b128: invisible to the memory legalizer, so the compiler does
// NOT insert s_waitcnt vmcnt(0) guards against outstanding global_load_lds.
// Synchronization is 100% manual (barrier + lgkmcnt + sched_barrier).
__device__ __forceinline__ v8s ldsr(unsigned byte_off) {
    v8s r;
    asm volatile("ds_read_b128 %0, %1" : "=v"(r) : "v"(byte_off));
    return r;
}

__device__ __forceinline__ float gelu_f(float t) {
    float u = t * (0.7978845608028654f + 0.03567740814183026f * t * t);
    return t / (1.0f + __expf(-2.0f * u));
}

// ---------------------------------------------------------------------------
// 128x128 2-phase GEMM, 2 blocks/CU. ONLY user: FC1 (1088 blocks).
// m-fast XCD chunk decode (R10-proven: FC1 dropped below the 70.3 us top-5
// floor; mechanism: ~64 concurrent blocks/XCD span 4 B-panels (1.2 MB) at a
// time instead of all 34 (10 MB > 4 MB L2 thrashed at FETCH 126 MB)).
// REQUIRES (nwg/8) % NNT == 0 (FC1: 136 = 4*34 ok).
// EPI: 2 = bf16(gelu(acc+bias))
// ---------------------------------------------------------------------------
template<int EPI>
__global__ __launch_bounds__(512, 4)
void gemm2p(const u16* __restrict__ A, const u16* __restrict__ B, int ld,
            int Kdim, const float* __restrict__ bias,
            const float* __restrict__ aux, float* __restrict__ outf,
            u16* __restrict__ outb, int ldc, int NNT)
{
    __shared__ __align__(128) union { u16 kl[2][16384]; float sc[8][64][17]; } sm;
    const int tid  = threadIdx.x, lane = tid & 63, wave = tid >> 6;
    const int wr   = wave >> 2, wc = wave & 3;
    const int fr   = lane & 15, kqh = lane >> 4;

    // XCD-compact, m-fast within chunk (L2 blocking; bijective when
    // chunk % NNT == 0)
    const int nwg   = gridDim.x;
    const int bidx  = (int)blockIdx.x;
    const int chunk = nwg >> 3;           // blocks per XCD
    const int xcd   = bidx & 7;
    const int j     = bidx >> 3;
    const int MXCD  = chunk / NNT;        // m-tiles per XCD
    const int mt    = xcd * MXCD + (j % MXCD);
    const int nt    = j / MXCD;
    const int bm0   = mt * 128, bn0 = nt * 128;

    // 16KB-half staging involution (identical to gemm8p)
    const int c    = tid;
    const int s_lr = (c >> 7) * 16 + ((c >> 2) & 15);
    const int s_lc = ((((c >> 6) & 1) * 4) + ((c & 3) ^ (((c >> 5) & 1) << 1))) * 8;
    const size_t s_off = (size_t)s_lr * ld + s_lc;
    const unsigned koff2 = (unsigned)(fr * 64 + ((kqh * 16) ^ ((fr & 8) << 2)));

    u16* kb = sm.kl[0];
    const unsigned lbase = lds_off(kb);

    auto stage = [&](int bi, int reg, const u16* gRowBase) {
        u16* lb = kb + bi * 16384 + reg * 4096;   // reg: 0 = A half, 2 = B half
        async16(gRowBase + s_off, lb + tid * 8);
        async16(gRowBase + s_off + (size_t)64 * ld, lb + (512 + tid) * 8);
    };
    auto srcA = [&](int t) { return A + (size_t)bm0 * ld + t * 64; };
    auto srcB = [&](int t) { return B + (size_t)bn0 * ld + t * 64; };

    v4f acc[4][2];
    const v4f vzero = {0.f, 0.f, 0.f, 0.f};
#pragma unroll
    for (int i = 0; i < 4; ++i) { acc[i][0] = vzero; acc[i][1] = vzero; }

    const int NKT = Kdim >> 6;

    // ---- prologue: tile0 fully + tile1's B half; vmcnt(2) => tile0 landed
    stage(0, 0, srcA(0));
    stage(0, 2, srcB(0));
    if (NKT > 1) {
        stage(1, 2, srcB(1));
        asm volatile("s_waitcnt vmcnt(2)" ::: "memory");
    } else {
        asm volatile("s_waitcnt vmcnt(0)" ::: "memory");
    }
    __builtin_amdgcn_s_barrier();

    v8s a[8], b0f[2], b1f[2];
    for (int t = 0; t < NKT; ++t) {
        const int bi = t & 1;
        const unsigned AB = lbase + bi * 32768;
        const unsigned BB = AB + 16384;

        // ---- P1: read everything; stage A(t+1); MFMA nj=0 ----------------
#pragma unroll
        for (int mi = 0; mi < 4; ++mi)
#pragma unroll
            for (int ks = 0; ks < 2; ++ks)
                a[mi * 2 + ks] = ldsr(AB + ((wr * 4 + mi) * 2 + ks) * 1024 + koff2);
#pragma unroll
        for (int ks = 0; ks < 2; ++ks)
            b0f[ks] = ldsr(BB + ((wc * 2 + 0) * 2 + ks) * 1024 + koff2);
#pragma unroll
        for (int ks = 0; ks < 2; ++ks)
            b1f[ks] = ldsr(BB + ((wc * 2 + 1) * 2 + ks) * 1024 + koff2);
        if (t + 1 < NKT) stage(bi ^ 1, 0, srcA(t + 1));
        __builtin_amdgcn_s_barrier();
        asm volatile("s_waitcnt lgkmcnt(0)" ::: "memory");
        __builtin_amdgcn_sched_barrier(0);
        __builtin_amdgcn_s_setprio(1);
#pragma unroll
        for (int mi = 0; mi < 4; ++mi)
#pragma unroll
            for (int ks = 0; ks < 2; ++ks)
                acc[mi][0] = __builtin_amdgcn_mfma_f32_16x16x32_bf16(
                    a[mi * 2 + ks], b0f[ks], acc[mi][0], 0, 0, 0);
        __builtin_amdgcn_s_setprio(0);
        __builtin_amdgcn_s_barrier();

        // ---- P2: stage B(t+2) into bi (reads of bi done); MFMA nj=1 ------
        if (t + 2 < NKT) stage(bi, 2, srcB(t + 2));
        __builtin_amdgcn_s_setprio(1);
#pragma unroll
        for (int mi = 0; mi < 4; ++mi)
#pragma unroll
            for (int ks = 0; ks < 2; ++ks)
                acc[mi][1] = __builtin_amdgcn_mfma_f32_16x16x32_bf16(
                    a[mi * 2 + ks], b1f[ks], acc[mi][1], 0, 0, 0);
        __builtin_amdgcn_s_setprio(0);
        if (t + 2 < NKT) { asm volatile("s_waitcnt vmcnt(2)" ::: "memory"); }
        else             { asm volatile("s_waitcnt vmcnt(0)" ::: "memory"); }
        __builtin_amdgcn_s_barrier();
    }

    // ---- epilogue: gemm_bt-style LDS transpose, JT=2 ---------------------
    const int cn = lane & 15;
    const int cm = (lane >> 4) * 4;
    float (*S)[17] = sm.sc[wave];
    const int gm = bm0 + wr * 64 + lane;
#pragma unroll
    for (int jp = 0; jp < 2; ++jp) {
        __syncthreads();
#pragma unroll
        for (int i = 0; i < 4; ++i)
#pragma unroll
            for (int r = 0; r < 4; ++r)
                S[i * 16 + cm + r][cn] = acc[i][jp][r];
        __syncthreads();
        const int gn0 = bn0 + wc * 32 + jp * 16;
        float v[16];
#pragma unroll
        for (int cc = 0; cc < 16; ++cc) v[cc] = S[lane][cc];
        union { u16 us[16]; uint4 q4[2]; } o;
#pragma unroll
        for (int cc = 0; cc < 16; ++cc) {
            float tv = v[cc];
            if constexpr (EPI >= 1) tv += bias[gn0 + cc];
            if constexpr (EPI == 2) tv = gelu_f(tv);
            o.us[cc] = f2b(tv);
        }
        uint4* dst = (uint4*)(outb + (size_t)gm * ldc + gn0);
        dst[0] = o.q4[0];
        dst[1] = o.q4[1];
    }
}

// ---------------------------------------------------------------------------
// 256x256 8-phase GEMM — round-4 schedule (proven). 1 block/CU; best for
// grids <= 256 blocks (single round). Used by QKV (224) and QKT (256).
// EPI: 0 = bf16 out; 1 = bf16(acc+bias) + fused V-transpose; 2 = gelu
// ---------------------------------------------------------------------------
template<int EPI>
__global__ __launch_bounds__(512, 2)
void gemm8p(const u16* __restrict__ A, const u16* __restrict__ B, int ld,
            int Kdim, const float* __restrict__ bias,
            u16* __restrict__ outb, int ldc, int NNT, u16* __restrict__ vt)
{
    __shared__ __align__(128) union { u16 kl[2][32768]; u16 ep[8][8192]; } sm;
    const int tid  = threadIdx.x, lane = tid & 63, wave = tid >> 6;
    const int wr   = wave >> 2, wc = wave & 3;
    const int fr   = lane & 15, kqh = lane >> 4;

    const int nwg  = gridDim.x;
    const int bidx = (int)blockIdx.x;
    const int wg   = (bidx & 7) * (nwg >> 3) + (bidx >> 3);
    const int mt   = wg / NNT, nt = wg % NNT;
    const int bm0  = mt * 256, bn0 = nt * 256;

    const int c    = tid;
    const int s_lr = (c >> 7) * 16 + ((c >> 2) & 15);
    const int s_lc = ((((c >> 6) & 1) * 4) + ((c & 3) ^ (((c >> 5) & 1) << 1))) * 8;
    const size_t s_off = (size_t)s_lr * ld + s_lc;
    const unsigned koff2 = (unsigned)(fr * 64 + ((kqh * 16) ^ ((fr & 8) << 2)));

    u16* kb = sm.kl[0];
    const unsigned lbase = lds_off(kb);

    auto stage = [&](int bi, int reg, const u16* gRowBase) {
        u16* lb = kb + bi * 32768 + reg * 4096;
        async16(gRowBase + s_off, lb + tid * 8);
        async16(gRowBase + s_off + (size_t)64 * ld, lb + (512 + tid) * 8);
    };
    auto srcA = [&](int h, int t) { return A + (size_t)(bm0 + h * 128) * ld + t * 64; };
    auto srcB = [&](int h, int t) { return B + (size_t)(bn0 + h * 128) * ld + t * 64; };

    v4f acc[8][4];
    const v4f vzero = {0.f, 0.f, 0.f, 0.f};
#pragma unroll
    for (int i = 0; i < 8; ++i)
#pragma unroll
        for (int j = 0; j < 4; ++j) acc[i][j] = vzero;

    const int NKT = Kdim >> 6;

    stage(0, 4, srcB(0, 0));
    stage(0, 6, srcB(1, 0));
    stage(0, 0, srcA(0, 0));
    stage(0, 2, srcA(1, 0));
    if (NKT > 1) {
        stage(1, 4, srcB(0, 1));
        stage(1, 6, srcB(1, 1));
        asm volatile("s_waitcnt vmcnt(4)" ::: "memory");
    } else {
        asm volatile("s_waitcnt vmcnt(0)" ::: "memory");
    }
    __builtin_amdgcn_s_barrier();

    v8s a[8], b0f[4], b1f[4];
    for (int t = 0; t < NKT; ++t) {
        const int bi = t & 1;
        const unsigned AB = lbase + bi * 65536 + wr * 16384;
        const unsigned BB = lbase + bi * 65536 + 32768 + (wc >> 1) * 16384;
        const unsigned bs = (wc & 1) * 8192;

        // phase 1
#pragma unroll
        for (int mi = 0; mi < 4; ++mi)
#pragma unroll
            for (int ks = 0; ks < 2; ++ks)
                a[mi * 2 + ks] = ldsr(AB + (mi * 2 + ks) * 1024 + koff2);
#pragma unroll
        for (int nj = 0; nj < 2; ++nj)
#pragma unroll
            for (int ks = 0; ks < 2; ++ks)
                b0f[nj * 2 + ks] = ldsr(BB + bs + (nj * 2 + ks) * 1024 + koff2);
        if (t + 1 < NKT) stage(bi ^ 1, 0, srcA(0, t + 1));
        __builtin_amdgcn_s_barrier();
        asm volatile("s_waitcnt lgkmcnt(0)" ::: "memory");
        __builtin_amdgcn_sched_barrier(0);
        __builtin_amdgcn_s_setprio(1);
#pragma unroll
        for (int mi = 0; mi < 4; ++mi)
#pragma unroll
            for (int nj = 0; nj < 2; ++nj)
#pragma unroll
                for (int ks = 0; ks < 2; ++ks)
                    acc[mi][nj] = __builtin_amdgcn_mfma_f32_16x16x32_bf16(
                        a[mi * 2 + ks], b0f[nj * 2 + ks], acc[mi][nj], 0, 0, 0);
        __builtin_amdgcn_s_setprio(0);
        __builtin_amdgcn_s_barrier();

        // phase 2
#pragma unroll
        for (int nj = 0; nj < 2; ++nj)
#pragma unroll
            for (int ks = 0; ks < 2; ++ks)
                b1f[nj * 2 + ks] = ldsr(BB + bs + (4 + nj * 2 + ks) * 1024 + koff2);
        if (t + 1 < NKT) stage(bi ^ 1, 2, srcA(1, t + 1));
        __builtin_amdgcn_s_barrier();
        asm volatile("s_waitcnt lgkmcnt(0)" ::: "memory");
        __builtin_amdgcn_sched_barrier(0);
        __builtin_amdgcn_s_setprio(1);
#pragma unroll
        for (int mi = 0; mi < 4; ++mi)
#pragma unroll
            for (int nj = 0; nj < 2; ++nj)
#pragma unroll
                for (int ks = 0; ks < 2; ++ks)
                    acc[mi][2 + nj] = __builtin_amdgcn_mfma_f32_16x16x32_bf16(
                        a[mi * 2 + ks], b1f[nj * 2 + ks], acc[mi][2 + nj], 0, 0, 0);
        __builtin_amdgcn_s_setprio(0);
        __builtin_amdgcn_s_barrier();

        // phase 3
#pragma unroll
        for (int mi = 0; mi < 4; ++mi)
#pragma unroll
            for (int ks = 0; ks < 2; ++ks)
                a[mi * 2 + ks] = ldsr(AB + (8 + mi * 2 + ks) * 1024 + koff2);
        if (t + 2 < NKT) stage(bi, 4, srcB(0, t + 2));
        __builtin_amdgcn_s_barrier();
        asm volatile("s_waitcnt lgkmcnt(0)" ::: "memory");
        __builtin_amdgcn_sched_barrier(0);
        __builtin_amdgcn_s_setprio(1);
#pragma unroll
        for (int mi = 0; mi < 4; ++mi)
#pragma unroll
            for (int nj = 0; nj < 2; ++nj)
#pragma unroll
                for (int ks = 0; ks < 2; ++ks)
                    acc[4 + mi][2 + nj] = __builtin_amdgcn_mfma_f32_16x16x32_bf16(
                        a[mi * 2 + ks], b1f[nj * 2 + ks], acc[4 + mi][2 + nj], 0, 0, 0);
        __builtin_amdgcn_s_setprio(0);
        __builtin_amdgcn_s_barrier();

        // phase 4
        if (t + 2 < NKT) stage(bi, 6, srcB(1, t + 2));
        __builtin_amdgcn_s_barrier();
        __builtin_amdgcn_s_setprio(1);
#pragma unroll
        for (int mi = 0; mi < 4; ++mi)
#pragma unroll
            for (int nj = 0; nj < 2; ++nj)
#pragma unroll
                for (int ks = 0; ks < 2; ++ks)
                    acc[4 + mi][nj] = __builtin_amdgcn_mfma_f32_16x16x32_bf16(
                        a[mi * 2 + ks], b0f[nj * 2 + ks], acc[4 + mi][nj], 0, 0, 0);
        __builtin_amdgcn_s_setprio(0);
        if (t + 2 < NKT) { asm volatile("s_waitcnt vmcnt(4)" ::: "memory"); }
        else             { asm volatile("s_waitcnt vmcnt(0)" ::: "memory"); }
        __builtin_amdgcn_s_barrier();
    }

    asm volatile("s_waitcnt vmcnt(0)" ::: "memory");
    __builtin_amdgcn_s_barrier();
    u16* ew = sm.ep[wave];
    float bcol[4];
    if constexpr (EPI >= 1) {
#pragma unroll
        for (int nj = 0; nj < 4; ++nj)
            bcol[nj] = bias[bn0 + wc * 64 + nj * 16 + fr];
    }
#pragma unroll
    for (int mi = 0; mi < 8; ++mi)
#pragma unroll
        for (int nj = 0; nj < 4; ++nj)
#pragma unroll
            for (int r = 0; r < 4; ++r) {
                int row = mi * 16 + kqh * 4 + r;
                int ec  = nj * 16 + fr;
                float t = acc[mi][nj][r];
                if constexpr (EPI >= 1) t += bcol[nj];
                if constexpr (EPI == 2) t = gelu_f(t);
                ew[row * 64 + (ec ^ (((row >> 2) & 3) << 4))] = f2b(t);
            }
    __syncthreads();
    const int gc = bn0 + wc * 64 + (lane & 7) * 8;
    const bool inV = (EPI == 1) && (vt != nullptr) && gc >= 2304 && gc < D3;
#pragma unroll
    for (int p = 0; p < 16; ++p) {
        int row = p * 8 + (lane >> 3);
        int key = (row >> 2) & 3;
        v8s ch = *(const v8s*)(ew + row * 64 + (((lane & 7) * 8) ^ (key << 4)));
        size_t gm = (size_t)(bm0 + wr * 128 + row);
        *(uint4*)(outb + gm * ldc + gc) = __builtin_bit_cast(uint4, ch);
        if constexpr (EPI == 1) {
            if (inV) {
                union { v8s v; u16 us[8]; } cu; cu.v = ch;
#pragma unroll
                for (int j = 0; j < 8; ++j)
                    vt[(size_t)(gc + j - 2304) * NT + gm] = cu.us[j];
            }
        }
    }
}

// ---------------------------------------------------------------------------
// GEMM: C[m][n] = sum_k A[m][k] * B[n][k]   (B transposed, K contiguous)
// DBUF=1 (MT=64): double-buffered LDS, one barrier per K-step. Proven best
// for the N=1152 family (576 blocks = 2.25 blocks/CU at 48KB LDS).
// EPI: 0 = bf16 out; 2 = bf16(gelu(acc+bias)); 3 = f32 out = aux + acc + bias;
//      4 = f32 out = acc + bias[n] + pos[n][m]  (aux = pos, [D][NT] layout)
// ---------------------------------------------------------------------------
template<int EPI, int MT, int DBUF = 0>
__global__ __launch_bounds__(256)
void gemm_bt(const u16* __restrict__ A, int lda,
             const u16* __restrict__ B, int ldb, int Kdim,
             const float* __restrict__ bias, const float* __restrict__ aux,
             float* __restrict__ outf, u16* __restrict__ outb, int ldc,
             u16* __restrict__ vt, int NX)
{
    constexpr int JT = (MT == 128) ? 4 : 2;
    constexpr int AR = MT * 8 / 256;
    constexpr int NB = DBUF ? 2 : 1;

    __shared__ union SM {
        struct { u16 a[NB * MT * 64]; u16 b[NB * 128 * 64]; } st;
        float sc[4][64][17];
    } sm;

    const int b    = blockIdx.x;
    const int MY   = (gridDim.x >> 3) / NX;
    const int q    = b >> 3;
    const int m0   = ((b & 7) * MY + q % MY) * MT;
    const int n0   = (q / MY) * 128;

    const int tid  = threadIdx.x;
    const int lane = tid & 63;
    const int wave = tid >> 6;
    const int wm   = (MT == 128) ? (wave & 1) * 64 : 0;
    const int wn   = (MT == 128) ? (wave >> 1) * 64 : wave * 32;
    const int fr   = lane & 15;
    const int kqh  = lane >> 4;
    const int swz  = fr & 7;

    v4f acc[4][JT];
    const v4f vzero = {0.f, 0.f, 0.f, 0.f};
#pragma unroll
    for (int i = 0; i < 4; ++i)
#pragma unroll
        for (int j = 0; j < JT; ++j) acc[i][j] = vzero;

    auto stage = [&](u16* As, u16* Bs, int kt) {
#pragma unroll
        for (int r = 0; r < AR; ++r) {
            int c = r * 256 + tid;
            int row = c >> 3;
            int kc = (c & 7) ^ (row & 7);
            async16(A + (size_t)(m0 + row) * lda + kt + kc * 8, As + c * 8);
        }
#pragma unroll
        for (int r = 0; r < 4; ++r) {
            int c = r * 256 + tid;
            int row = c >> 3;
            int kc = (c & 7) ^ (row & 7);
            async16(B + (size_t)(n0 + row) * ldb + kt + kc * 8, Bs + c * 8);
        }
    };

    auto compute = [&](const u16* As, const u16* Bs) {
#pragma unroll
        for (int ks = 0; ks < 2; ++ks) {
            const int kq = ks * 4 + kqh;
            const int kp = (kq ^ swz) * 8;
            v8s af[4], bf[JT];
#pragma unroll
            for (int i = 0; i < 4; ++i)
                af[i] = *(const v8s*)(As + (wm + i * 16 + fr) * 64 + kp);
#pragma unroll
            for (int j = 0; j < JT; ++j)
                bf[j] = *(const v8s*)(Bs + (wn + j * 16 + fr) * 64 + kp);
#pragma unroll
            for (int i = 0; i < 4; ++i)
#pragma unroll
                for (int j = 0; j < JT; ++j)
                    acc[i][j] = __builtin_amdgcn_mfma_f32_16x16x32_bf16(
                        af[i], bf[j], acc[i][j], 0, 0, 0);
        }
    };

    if constexpr (DBUF) {
        stage(sm.st.a, sm.st.b, 0);
        int cur = 0;
        for (int kt = 0; kt < Kdim; kt += 64) {
            __syncthreads();
            const int nxt = cur ^ 1;
            if (kt + 64 < Kdim)
                stage(sm.st.a + nxt * (MT * 64), sm.st.b + nxt * (128 * 64), kt + 64);
            compute(sm.st.a + cur * (MT * 64), sm.st.b + cur * (128 * 64));
            cur = nxt;
        }
    } else {
        for (int kt = 0; kt < Kdim; kt += 64) {
            stage(sm.st.a, sm.st.b, kt);
            __syncthreads();
            compute(sm.st.a, sm.st.b);
            __syncthreads();
        }
    }

    const int cn = lane & 15;
    const int cm = (lane >> 4) * 4;
    float (*S)[17] = sm.sc[wave];
    const int gm = m0 + wm + lane;
#pragma unroll
    for (int jp = 0; jp < JT; ++jp) {
        __syncthreads();
#pragma unroll
        for (int i = 0; i < 4; ++i)
#pragma unroll
            for (int r = 0; r < 4; ++r)
                S[i * 16 + cm + r][cn] = acc[i][jp][r];
        __syncthreads();
        const int gn0 = n0 + wn + jp * 16;
        float v[16];
#pragma unroll
        for (int c = 0; c < 16; ++c) v[c] = S[lane][c];
        if constexpr (EPI <= 2) {
            union { u16 us[16]; uint4 q4[2]; } o;
#pragma unroll
            for (int c = 0; c < 16; ++c) {
                float t = v[c];
                if constexpr (EPI >= 1) t += bias[gn0 + c];
                if constexpr (EPI == 2) t = gelu_f(t);
                o.us[c] = f2b(t);
            }
            uint4* dst = (uint4*)(outb + (size_t)gm * ldc + gn0);
            dst[0] = o.q4[0];
            dst[1] = o.q4[1];
            if constexpr (EPI == 1) {
                if (vt != nullptr && gn0 >= 2304) {
#pragma unroll
                    for (int c = 0; c < 16; ++c)
                        vt[(size_t)(gn0 + c - 2304) * NT + gm] = o.us[c];
                }
            }
        } else if constexpr (EPI == 3) {
            float* dst = outf + (size_t)gm * ldc + gn0;
            const float* ax = aux + (size_t)gm * ldc + gn0;
#pragma unroll
            for (int c = 0; c < 4; ++c) {
                float4 a4 = ((const float4*)ax)[c];
                float4 r4;
                r4.x = a4.x + v[4 * c + 0] + bias[gn0 + 4 * c + 0];
                r4.y = a4.y + v[4 * c + 1] + bias[gn0 + 4 * c + 1];
                r4.z = a4.z + v[4 * c + 2] + bias[gn0 + 4 * c + 2];
                r4.w = a4.w + v[4 * c + 3] + bias[gn0 + 4 * c + 3];
                ((float4*)dst)[c] = r4;
            }
        } else {
            float* dst = outf + (size_t)gm * ldc + gn0;
#pragma unroll
            for (int c = 0; c < 4; ++c) {
                float4 r4;
                r4.x = v[4 * c + 0] + bias[gn0 + 4 * c + 0] + aux[(size_t)(gn0 + 4 * c + 0) * NT + gm];
                r4.y = v[4 * c + 1] + bias[gn0 + 4 * c + 1] + aux[(size_t)(gn0 + 4 * c + 1) * NT + gm];
                r4.z = v[4 * c + 2] + bias[gn0 + 4 * c + 2] + aux[(size_t)(gn0 + 4 * c + 2) * NT + gm];
                r4.w = v[4 * c + 3] + bias[gn0 + 4 * c + 3] + aux[(size_t)(gn0 + 4 * c + 3) * NT + gm];
                ((float4*)dst)[c] = r4;
            }
        }
    }
}

// ---------------------------------------------------------------------------
// LayerNorm over D=1152. 384 threads, 3 elems each. OUTF=1 -> f32, else bf16.
// ---------------------------------------------------------------------------
template<int OUTF>
__global__ __launch_bounds__(384)
void ln_kernel(const float* __restrict__ x, const float* __restrict__ w,
               const float* __restrict__ b, void* __restrict__ out)
{
    const int n = blockIdx.x;
    const int t = threadIdx.x;
    const float* row = x + (size_t)n * DD;
    float v0 = row[t], v1 = row[t + 384], v2 = row[t + 768];
    float s  = v0 + v1 + v2;
    float ss = v0 * v0 + v1 * v1 + v2 * v2;
#pragma unroll
    for (int o = 32; o > 0; o >>= 1) {
        s  += __shfl_down(s, o);
        ss += __shfl_down(ss, o);
    }
    __shared__ float ps[6], pss[6], mh[2];
    if ((t & 63) == 0) { ps[t >> 6] = s; pss[t >> 6] = ss; }
    __syncthreads();
    if (t == 0) {
        float S = 0.f, SS = 0.f;
        for (int i = 0; i < 6; ++i) { S += ps[i]; SS += pss[i]; }
        float m = S / (float)DD;
        float var = SS / (float)DD - m * m;
        mh[0] = m;
        mh[1] = rsqrtf(var + 1e-6f);
    }
    __syncthreads();
    const float m = mh[0], rs = mh[1];
#pragma unroll
    for (int j = 0; j < 3; ++j) {
        int c = t + j * 384;
        float y = (row[c] - m) * rs * w[c] + b[c];
        if constexpr (OUTF) ((float*)out)[(size_t)n * DD + c] = y;
        else                ((u16*)out)[(size_t)n * DD + c]   = f2b(y);
    }
}

// ---------------------------------------------------------------------------
// Softmax over rows of bf16 scores [NT x NT], in place, with scale.
// ---------------------------------------------------------------------------
__global__ __launch_bounds__(256)
void softmax_kernel(u16* __restrict__ s)
{
    const float SC = 0.029462782549439484f;  // 1/sqrt(1152)
    const int row = blockIdx.x;
    const int t = threadIdx.x;
    u16* p = s + (size_t)row * NT + t * 16;
    uint4 u0 = *(const uint4*)p;
    uint4 u1 = *(const uint4*)(p + 8);
    float v[16];
    unsigned int w[8] = {u0.x, u0.y, u0.z, u0.w, u1.x, u1.y, u1.z, u1.w};
#pragma unroll
    for (int i = 0; i < 8; ++i) {
        v[2 * i]     = b2f((u16)(w[i] & 0xffffu)) * SC;
        v[2 * i + 1] = b2f((u16)(w[i] >> 16)) * SC;
    }
    float mx = -1e30f;
#pragma unroll
    for (int i = 0; i < 16; ++i) mx = fmaxf(mx, v[i]);
#pragma unroll
    for (int o = 32; o > 0; o >>= 1) mx = fmaxf(mx, __shfl_down(mx, o));
    __shared__ float red[4];
    __shared__ float bc;
    if ((t & 63) == 0) red[t >> 6] = mx;
    __syncthreads();
    if (t == 0) bc = fmaxf(fmaxf(red[0], red[1]), fmaxf(red[2], red[3]));
    __syncthreads();
    const float M = bc;
    float sum = 0.f;
#pragma unroll
    for (int i = 0; i < 16; ++i) { v[i] = __expf(v[i] - M); sum += v[i]; }
#pragma unroll
    for (int o = 32; o > 0; o >>= 1) sum += __shfl_down(sum, o);
    __syncthreads();
    if ((t & 63) == 0) red[t >> 6] = sum;
    __syncthreads();
    if (t == 0) bc = red[0] + red[1] + red[2] + red[3];
    __syncthreads();
    const float inv = 1.0f / bc;
    union { u16 us[8]; uint4 u4; } o0, o1;
#pragma unroll
    for (int i = 0; i < 8; ++i) o0.us[i] = f2b(v[i] * inv);
#pragma unroll
    for (int i = 0; i < 8; ++i) o1.us[i] = f2b(v[8 + i] * inv);
    *(uint4*)p = o0.u4;
    *(uint4*)(p + 8) = o1.u4;
}

// ---------------------------------------------------------------------------
// im2col: img [3][896][896] -> a [NT][KP] bf16 (k = cin*196+py*14+px, pad->0)
// ---------------------------------------------------------------------------
__global__ __launch_bounds__(256)
void im2col_kernel(const float* __restrict__ img, u16* __restrict__ a)
{
    const int k = blockIdx.x * 256 + threadIdx.x;
    const int n = blockIdx.y;
    if (k >= KP) return;
    float v = 0.f;
    if (k < 588) {
        int cin = k / 196;
        int rr = k - cin * 196;
        int py = rr / 14;
        int px = rr - py * 14;
        int gy = (n >> 6) * 14 + py;
        int gx = (n & 63) * 14 + px;
        v = img[(size_t)cin * 896 * 896 + (size_t)gy * 896 + gx];
    }
    a[(size_t)n * KP + k] = f2b(v);
}

// ---------------------------------------------------------------------------
// One fused, float4-vectorized weight conversion/pad kernel.
// QKV weights/bias PADDED to D3P=3584 rows (zeros beyond 3456).
// ---------------------------------------------------------------------------
constexpr int CV_S0 = 2 * D3P * DD / 4;
constexpr int CV_S1 = CV_S0 + 2 * DD * DD / 4;
constexpr int CV_S2 = CV_S1 + 2 * MLP_P * DD / 4;
constexpr int CV_S3 = CV_S2 + 2 * DD * MLP_P / 4;
constexpr int CV_S4 = CV_S3 + DD * KP / 4;
constexpr int CV_S5 = CV_S4 + 2 * MLP_P / 4;
constexpr int CV_S6 = CV_S5 + 2 * D3P / 4;
constexpr int CV_BLOCKS = (CV_S6 + 255) / 256;

__device__ __forceinline__ void store_bf4(u16* p, float4 f) {
    union { u16 s[4]; uint2 d; } o;
    o.s[0] = f2b(f.x); o.s[1] = f2b(f.y); o.s[2] = f2b(f.z); o.s[3] = f2b(f.w);
    *(uint2*)p = o.d;
}

__global__ __launch_bounds__(256)
void convert_all(const float* __restrict__ qkv_w, const float* __restrict__ proj_w,
                 const float* __restrict__ fc1_w, const float* __restrict__ fc2_w,
                 const float* __restrict__ patch_w, const float* __restrict__ fc1_b,
                 const float* __restrict__ qkv_b,
                 u16* __restrict__ w_qkv, u16* __restrict__ w_proj,
                 u16* __restrict__ w_fc1, u16* __restrict__ w_fc2,
                 u16* __restrict__ w_pat, float* __restrict__ fc1b_p,
                 float* __restrict__ qkvb_p)
{
    int v = blockIdx.x * 256 + threadIdx.x;
    if (v >= CV_S6) return;
    const float4 z4 = {0.f, 0.f, 0.f, 0.f};
    if (v < CV_S0) {
        size_t e = (size_t)v * 4;
        int row = (int)(e / DD);
        int c = (int)(e % DD);
        int l = row / D3P, lr = row % D3P;
        float4 f = z4;
        if (lr < D3)
            f = *(const float4*)(qkv_w + ((size_t)l * D3 + lr) * DD + c);
        store_bf4(w_qkv + e, f);
    } else if (v < CV_S1) {
        int e = v - CV_S0;
        store_bf4(w_proj + (size_t)e * 4, ((const float4*)proj_w)[e]);
    } else if (v < CV_S2) {
        size_t e = (size_t)(v - CV_S1) * 4;
        int row = (int)(e / DD);
        int c = (int)(e % DD);
        int l = row / MLP_P, lr = row % MLP_P;
        float4 f = z4;
        if (lr < MLP_R)
            f = *(const float4*)(fc1_w + ((size_t)l * MLP_R + lr) * DD + c);
        store_bf4(w_fc1 + e, f);
    } else if (v < CV_S3) {
        size_t e = (size_t)(v - CV_S2) * 4;
        int row = (int)(e / MLP_P);
        int c = (int)(e % MLP_P);
        float4 f = z4;
        if (c < MLP_R)
            f = *(const float4*)(fc2_w + (size_t)row * MLP_R + c);
        store_bf4(w_fc2 + e, f);
    } else if (v < CV_S4) {
        size_t e = (size_t)(v - CV_S3) * 4;
        int row = (int)(e / KP);
        int c = (int)(e % KP);
        float4 f = z4;
        if (c < 588)
            f = *(const float4*)(patch_w + (size_t)row * 588 + c);
        store_bf4(w_pat + e, f);
    } else if (v < CV_S5) {
        size_t e = (size_t)(v - CV_S4) * 4;
        int l = (int)(e / MLP_P);
        int c = (int)(e % MLP_P);
        float4 f = z4;
        if (c < MLP_R)
            f = *(const float4*)(fc1_b + (size_t)l * MLP_R + c);
        *(float4*)(fc1b_p + e) = f;
    } else {
        size_t e = (size_t)(v - CV_S5) * 4;
        int l = (int)(e / D3P);
        int c = (int)(e % D3P);
        float4 f = z4;
        if (c < D3)
            f = *(const float4*)(qkv_b + (size_t)l * D3 + c);
        *(float4*)(qkvb_p + e) = f;
    }
}

// ---------------------------------------------------------------------------
// Workspace layout (bytes)
// ---------------------------------------------------------------------------
constexpr size_t OFF_X      = 0;                                  // f32 [NT][DD]
constexpr size_t OFF_HBF    = OFF_X      + (size_t)NT * DD * 4;   // bf16 [NT][DD]
constexpr size_t OFF_TMP    = OFF_HBF    + (size_t)NT * DD * 2;   // bf16 max(NT*MLP_P, NT*NT)
constexpr size_t OFF_QKV    = OFF_TMP    + (size_t)NT * MLP_P * 2;// bf16 [NT][D3P]
constexpr size_t OFF_VT     = OFF_QKV    + (size_t)NT * D3P * 2;  // bf16 [DD][NT]
constexpr size_t OFF_IM     = OFF_VT     + (size_t)DD * NT * 2;   // bf16 [NT][KP]
constexpr size_t OFF_WQKV   = OFF_IM     + (size_t)NT * KP * 2;   // bf16 [2][D3P][DD]
constexpr size_t OFF_WPROJ  = OFF_WQKV   + (size_t)2 * D3P * DD * 2;
constexpr size_t OFF_WFC1   = OFF_WPROJ  + (size_t)2 * DD * DD * 2;   // [2][MLP_P][DD]
constexpr size_t OFF_WFC2   = OFF_WFC1   + (size_t)2 * MLP_P * DD * 2;// [2][DD][MLP_P]
constexpr size_t OFF_WPATCH = OFF_WFC2   + (size_t)2 * DD * MLP_P * 2;// [DD][KP]
constexpr size_t OFF_FC1B   = OFF_WPATCH + (size_t)DD * KP * 2;       // f32 [2][MLP_P]
constexpr size_t OFF_QKVB   = OFF_FC1B   + (size_t)2 * MLP_P * 4;     // f32 [2][D3P]

extern "C" void kernel_launch(void* const* d_in, const int* in_sizes, int n_in,
                              void* d_out, int out_size, void* d_ws, size_t ws_size,
                              hipStream_t stream)
{
    const float* img     = (const float*)d_in[0];
    const float* patch_w = (const float*)d_in[1];
    const float* patch_b = (const float*)d_in[2];
    const float* pos     = (const float*)d_in[3];
    const float* ln1_w   = (const float*)d_in[4];
    const float* ln1_b   = (const float*)d_in[5];
    const float* qkv_w   = (const float*)d_in[6];
    const float* qkv_b   = (const float*)d_in[7];
    const float* proj_w  = (const float*)d_in[8];
    const float* proj_b  = (const float*)d_in[9];
    const float* ln2_w   = (const float*)d_in[10];
    const float* ln2_b   = (const float*)d_in[11];
    const float* fc1_w   = (const float*)d_in[12];
    const float* fc1_b   = (const float*)d_in[13];
    const float* fc2_w   = (const float*)d_in[14];
    const float* fc2_b   = (const float*)d_in[15];
    const float* post_w  = (const float*)d_in[16];
    const float* post_b  = (const float*)d_in[17];

    char* ws = (char*)d_ws;
    float* x      = (float*)(ws + OFF_X);
    u16*  h_bf    = (u16*)(ws + OFF_HBF);
    u16*  tmp_bf  = (u16*)(ws + OFF_TMP);
    u16*  qkv_bf  = (u16*)(ws + OFF_QKV);
    u16*  vt      = (u16*)(ws + OFF_VT);
    u16*  a_im    = (u16*)(ws + OFF_IM);
    u16*  w_qkv   = (u16*)(ws + OFF_WQKV);
    u16*  w_proj  = (u16*)(ws + OFF_WPROJ);
    u16*  w_fc1   = (u16*)(ws + OFF_WFC1);
    u16*  w_fc2   = (u16*)(ws + OFF_WFC2);
    u16*  w_pat   = (u16*)(ws + OFF_WPATCH);
    float* fc1b_p = (float*)(ws + OFF_FC1B);
    float* qkvb_p = (float*)(ws + OFF_QKVB);

    // ---- fused weight/bias conversion (1 dispatch) + im2col ----
    convert_all<<<CV_BLOCKS, 256, 0, stream>>>(
        qkv_w, proj_w, fc1_w, fc2_w, patch_w, fc1_b, qkv_b,
        w_qkv, w_proj, w_fc1, w_fc2, w_pat, fc1b_p, qkvb_p);
    im2col_kernel<<<dim3(3, NT), 256, 0, stream>>>(img, a_im);

    // ---- patch embed: x = im2col * patch_w^T + patch_b + pos (fused T) ----
    gemm_bt<4, 64, 1><<<9 * 64, 256, 0, stream>>>(
        a_im, KP, w_pat, KP, KP, patch_b, pos, x, nullptr, DD, nullptr, 9);

    for (int l = 0; l < 2; ++l) {
        // LN1 -> bf16
        ln_kernel<0><<<NT, 384, 0, stream>>>(x, ln1_w + l * DD, ln1_b + l * DD, h_bf);
        // QKV = h * Wqkv^T + b  (padded N=3584: 224 blocks; fused V-transpose)
        gemm8p<1><<<224, 512, 0, stream>>>(
            h_bf, w_qkv + (size_t)l * D3P * DD, DD, DD,
            qkvb_p + (size_t)l * D3P, qkv_bf, D3P, 14, vt);
        // scores = Q K^T  (16x16 tiles = 256 blocks, single round)
        gemm8p<0><<<256, 512, 0, stream>>>(
            qkv_bf, qkv_bf + DD, D3P, DD, nullptr, tmp_bf, NT, 16, nullptr);
        // softmax rows (in place)
        softmax_kernel<<<NT, 256, 0, stream>>>(tmp_bf);
        // attn_out = P * V   (B = V^T)
        gemm_bt<0, 64, 1><<<9 * 64, 256, 0, stream>>>(
            tmp_bf, NT, vt, NT, NT, nullptr, nullptr, nullptr, h_bf, DD, nullptr, 9);
        // x += attn_out * Wproj^T + b
        gemm_bt<3, 64, 1><<<9 * 64, 256, 0, stream>>>(
            h_bf, DD, w_proj + (size_t)l * DD * DD, DD, DD,
            proj_b + (size_t)l * DD, x, x, nullptr, DD, nullptr, 9);
        // LN2 -> bf16
        ln_kernel<0><<<NT, 384, 0, stream>>>(x, ln2_w + l * DD, ln2_b + l * DD, h_bf);
        // h2 = gelu(h * Wfc1^T + b)  (gemm2p, 1088 blocks, 2 blocks/CU,
        // m-fast XCD decode for L2 blocking — R10 per-dispatch win)
        gemm2p<2><<<1088, 512, 0, stream>>>(
            h_bf, w_fc1 + (size_t)l * MLP_P * DD, DD, DD,
            fc1b_p + (size_t)l * MLP_P, nullptr, nullptr, tmp_bf, MLP_P, 34);
        // x += h2 * Wfc2^T + b
        gemm_bt<3, 64, 1><<<9 * 64, 256, 0, stream>>>(
            tmp_bf, MLP_P, w_fc2 + (size_t)l * DD * MLP_P, MLP_P, MLP_P,
            fc2_b + (size_t)l * DD, x, x, nullptr, DD, nullptr, 9);
    }
    // final LN -> f32 d_out
    ln_kernel<1><<<NT, 384, 0, stream>>>(x, post_w, post_b, d_out);
}